// Round 4
// baseline (516.026 us; speedup 1.0000x reference)
//
#include <hip/hip_runtime.h>
#include <math.h>

#define NE 200000
#define NN 25000

static constexpr float INV_SQRT3  = 0.5773502691896258f;
static constexpr float INV_SQRT2  = 0.7071067811865476f;
static constexpr float INV_SQRT8  = 0.3535533905932738f;
static constexpr float INV_SQRT24 = 0.2041241452319315f;

typedef __attribute__((ext_vector_type(8))) short bf16x8;
typedef __attribute__((ext_vector_type(4))) float f32x4;

union U16x8 { uint4 u; bf16x8 v; };

__device__ __forceinline__ unsigned f2bf1(float f) {
  unsigned u = __float_as_uint(f);
  return (u + 0x7FFFu + ((u >> 16) & 1u)) >> 16;
}
__device__ __forceinline__ unsigned packbf(float a, float b) {
  return f2bf1(a) | (f2bf1(b) << 16);
}
__device__ __forceinline__ float bflo(unsigned u) { return __uint_as_float(u << 16); }
__device__ __forceinline__ float bfhi(unsigned u) { return __uint_as_float(u & 0xFFFF0000u); }

// ---------------- prep ----------------
// W1T transpose (fp32) + W2 pre-fragmented into MFMA A-operand layout (bf16).
__global__ __launch_bounds__(256) void prep_kernel(
    const float* __restrict__ kW1, const float* __restrict__ kW2,
    const float* __restrict__ vW1, const float* __restrict__ vW2,
    float* __restrict__ kW1T, float* __restrict__ vW1T,
    unsigned short* __restrict__ afrag)
{
  int t = blockIdx.x * blockDim.x + threadIdx.x;
  if (t < 1024) {
    int j = t >> 6;      // 0..15
    int r = t & 63;      // 0..63
    kW1T[r * 16 + j] = kW1[t];
    vW1T[r * 16 + j] = vW1[t];
  }
  if (t < 40960) {
    int j    = t & 7;
    int lane = (t >> 3) & 63;
    int kk   = (t >> 9) & 1;
    int ot   = (t >> 10) & 1;
    int ci   = t >> 11;           // 0..19
    int b    = ci / 10;
    int rem  = ci - b * 10;
    int p    = rem >> 1;
    int hf   = rem & 1;
    int r    = kk * 32 + ((lane >> 4) << 3) + j;
    int o    = p * 64 + hf * 32 + ot * 16 + (lane & 15);
    const float* W = b ? vW2 : kW2;
    afrag[t] = (unsigned short)f2bf1(W[r * 320 + o]);
  }
}

// ---------------- per-node q precompute ----------------
__global__ __launch_bounds__(256) void node_kernel(
    const float* __restrict__ node_attr,
    const float* __restrict__ Wq0, const float* __restrict__ Wq1,
    const float* __restrict__ Wd0, const float* __restrict__ Wd1,
    float* __restrict__ qd, float* __restrict__ qvd)
{
  int n = blockIdx.x * blockDim.x + threadIdx.x;
  if (n >= NN) return;
  float ns[8], nv[24];
#pragma unroll
  for (int i = 0; i < 8; ++i)  ns[i] = node_attr[n * 32 + i];
#pragma unroll
  for (int i = 0; i < 24; ++i) nv[i] = node_attr[n * 32 + 8 + i];

  float qs[8];
#pragma unroll
  for (int m = 0; m < 8; ++m) {
    float a = 0.f;
#pragma unroll
    for (int i = 0; i < 8; ++i) a = fmaf(ns[i], Wq0[i * 8 + m], a);
    qs[m] = a * INV_SQRT8;
  }
#pragma unroll
  for (int k = 0; k < 8; ++k) {
    float a = 0.f;
#pragma unroll
    for (int m = 0; m < 8; ++m) a = fmaf(qs[m], Wd0[m * 8 + k], a);
    qd[n * 8 + k] = a;
  }
  float qv[24];
#pragma unroll
  for (int k = 0; k < 8; ++k) {
#pragma unroll
    for (int c = 0; c < 3; ++c) {
      float a = 0.f;
#pragma unroll
      for (int m = 0; m < 8; ++m) a = fmaf(nv[m * 3 + c], Wq1[m * 8 + k], a);
      qv[k * 3 + c] = a * INV_SQRT8;
    }
  }
#pragma unroll
  for (int k = 0; k < 8; ++k) {
#pragma unroll
    for (int c = 0; c < 3; ++c) {
      float a = 0.f;
#pragma unroll
      for (int m = 0; m < 8; ++m) a = fmaf(qv[m * 3 + c], Wd1[m * 8 + k], a);
      qvd[n * 24 + k * 3 + c] = a;
    }
  }
}

// ---------------- main edge pass (MFMA, fused aggregation) ----------------
// Per block: 256 edges, 4 waves x 64 edges. Branch 0 (k): logits -> exp ->
// z_sum/cnt atomics, exp kept in a register. Branch 1 (v): values scaled by
// sqrt(exp) are atomically aggregated straight into out[dst] (the rsqrt(z)
// factor is applied per-node afterwards by zscale_kernel).
// NOTE: no launch_bounds min-wave cap — R3's (256,2) forced 128 VGPR and
// spilled ~200 MB/dispatch of scratch traffic.
__global__ __launch_bounds__(256) void edge_kernel(
    const float* __restrict__ node_attr,
    const int*   __restrict__ edge_index,
    const float* __restrict__ edge_attr,
    const float* __restrict__ edge_sh,
    const float* __restrict__ kW1T, const float* __restrict__ vW1T,
    const unsigned short* __restrict__ afrag,
    const float* __restrict__ qd,   const float* __restrict__ qvd,
    float* __restrict__ out,
    float* __restrict__ z_sum, float* __restrict__ cnt)
{
  __shared__ unsigned char smem[65536];
  float* sW1 = (float*)smem;                              // 8 KiB
  const int tid  = threadIdx.x;
  const int lane = tid & 63;
  const int wave = tid >> 6;
  const int l15  = lane & 15;
  const int quad = lane >> 4;
  unsigned char* sh  = smem + 8192  + wave * 9216;        // 64 x 144 B
  unsigned char* swp = smem + 45056 + wave * 5120;        // 64 x 80 B

  // stage both W1T (2048 floats)
  ((float4*)sW1)[tid]       = ((const float4*)kW1T)[tid];
  ((float4*)sW1)[256 + tid] = ((const float4*)vW1T)[tid];
  __syncthreads();

  const int e = blockIdx.x * 256 + tid;
  const bool valid = (e < NE);
  const int el  = valid ? e : (NE - 1);
  const int src = edge_index[el];
  const int dst = edge_index[NE + el];

  const float s0  = edge_sh[el * 4 + 0];
  const float s1x = edge_sh[el * 4 + 1];
  const float s1y = edge_sh[el * 4 + 2];
  const float s1z = edge_sh[el * 4 + 3];

  float ea[16];
  {
    const float4* ea4 = (const float4*)(edge_attr + (size_t)el * 16);
#pragma unroll
    for (int i = 0; i < 4; ++i) {
      float4 v = ea4[i];
      ea[4*i+0] = v.x; ea[4*i+1] = v.y; ea[4*i+2] = v.z; ea[4*i+3] = v.w;
    }
  }
  float xs[8], xv[8][3];
  {
    const float4* na4 = (const float4*)(node_attr + (size_t)src * 32);
    float tmp[32];
#pragma unroll
    for (int i = 0; i < 8; ++i) {
      float4 v = na4[i];
      tmp[4*i+0] = v.x; tmp[4*i+1] = v.y; tmp[4*i+2] = v.z; tmp[4*i+3] = v.w;
    }
#pragma unroll
    for (int m = 0; m < 8; ++m) xs[m] = tmp[m];
#pragma unroll
    for (int m = 0; m < 8; ++m) {
      xv[m][0] = tmp[8 + 3*m + 0];
      xv[m][1] = tmp[8 + 3*m + 1];
      xv[m][2] = tmp[8 + 3*m + 2];
    }
  }

  const uint4* AF = (const uint4*)afrag;
  float ex = 0.f;   // exp(logit), carried from branch 0 to branch 1

#pragma unroll 1
  for (int b = 0; b < 2; ++b) {
    // ---- h = silu(ea @ W1 / 4) ----
    const float* W1base = sW1 + b * 1024;
    float h[64];
#pragma unroll
    for (int r = 0; r < 64; ++r) {
      const float4* rp = (const float4*)(W1base + r * 16);
      float4 x0 = rp[0], x1 = rp[1], x2 = rp[2], x3 = rp[3];
      float a0 = 0.f, a1 = 0.f;
      a0 = fmaf(ea[ 0], x0.x, a0); a0 = fmaf(ea[ 1], x0.y, a0);
      a0 = fmaf(ea[ 2], x0.z, a0); a0 = fmaf(ea[ 3], x0.w, a0);
      a1 = fmaf(ea[ 4], x1.x, a1); a1 = fmaf(ea[ 5], x1.y, a1);
      a1 = fmaf(ea[ 6], x1.z, a1); a1 = fmaf(ea[ 7], x1.w, a1);
      a0 = fmaf(ea[ 8], x2.x, a0); a0 = fmaf(ea[ 9], x2.y, a0);
      a0 = fmaf(ea[10], x2.z, a0); a0 = fmaf(ea[11], x2.w, a0);
      a1 = fmaf(ea[12], x3.x, a1); a1 = fmaf(ea[13], x3.y, a1);
      a1 = fmaf(ea[14], x3.z, a1); a1 = fmaf(ea[15], x3.w, a1);
      float a = (a0 + a1) * 0.25f;
      h[r] = a / (1.f + __expf(-a));
    }

    // ---- h -> bf16 -> sh[lane][.] ----
    {
      unsigned char* myrow = sh + lane * 144;
#pragma unroll
      for (int i = 0; i < 8; ++i) {
        uint4 pk;
        pk.x = packbf(h[8*i+0], h[8*i+1]);
        pk.y = packbf(h[8*i+2], h[8*i+3]);
        pk.z = packbf(h[8*i+4], h[8*i+5]);
        pk.w = packbf(h[8*i+6], h[8*i+7]);
        *(uint4*)(myrow + i * 16) = pk;
      }
    }

    // ---- B-fragments (H), read once, reused for all 10 chunks ----
    bf16x8 B[4][2];
#pragma unroll
    for (int et = 0; et < 4; ++et) {
#pragma unroll
      for (int kk = 0; kk < 2; ++kk) {
        U16x8 cv;
        cv.u = *(const uint4*)(sh + (et*16 + l15) * 144 + kk * 64 + quad * 16);
        B[et][kk] = cv.v;
      }
    }

    float accs[8];
    float accv[8][3];
#pragma unroll
    for (int n = 0; n < 8; ++n) {
      accs[n] = 0.f;
      accv[n][0] = 0.f; accv[n][1] = 0.f; accv[n][2] = 0.f;
    }

#pragma unroll
    for (int p = 0; p < 5; ++p) {
#pragma unroll
      for (int hf = 0; hf < 2; ++hf) {
        const int ci = b * 10 + p * 2 + hf;
        U16x8 a00, a01, a10, a11;
        a00.u = AF[(ci*4 + 0) * 64 + lane];
        a01.u = AF[(ci*4 + 1) * 64 + lane];
        a10.u = AF[(ci*4 + 2) * 64 + lane];
        a11.u = AF[(ci*4 + 3) * 64 + lane];

        // GEMM: C[o(32)][e(64)] = A @ H, C -> sw (bf16)
#pragma unroll
        for (int et = 0; et < 4; ++et) {
          f32x4 c0 = {0.f, 0.f, 0.f, 0.f};
          f32x4 c1 = {0.f, 0.f, 0.f, 0.f};
          c0 = __builtin_amdgcn_mfma_f32_16x16x32_bf16(a00.v, B[et][0], c0, 0, 0, 0);
          c0 = __builtin_amdgcn_mfma_f32_16x16x32_bf16(a01.v, B[et][1], c0, 0, 0, 0);
          c1 = __builtin_amdgcn_mfma_f32_16x16x32_bf16(a10.v, B[et][0], c1, 0, 0, 0);
          c1 = __builtin_amdgcn_mfma_f32_16x16x32_bf16(a11.v, B[et][1], c1, 0, 0, 0);
          unsigned char* wrow = swp + (et*16 + l15) * 80;
          uint2 p0; p0.x = packbf(c0.x, c0.y); p0.y = packbf(c0.z, c0.w);
          uint2 p1; p1.x = packbf(c1.x, c1.y); p1.y = packbf(c1.z, c1.w);
          *(uint2*)(wrow + quad * 8)      = p0;
          *(uint2*)(wrow + 32 + quad * 8) = p1;
        }

        // ---- contraction: lane reads its own 32 w values ----
        float wv[32];
        {
          const uint4* wr = (const uint4*)(swp + (size_t)lane * 80);
          uint4 q0 = wr[0], q1 = wr[1], q2 = wr[2], q3 = wr[3];
          unsigned qs_[16] = {q0.x,q0.y,q0.z,q0.w, q1.x,q1.y,q1.z,q1.w,
                              q2.x,q2.y,q2.z,q2.w, q3.x,q3.y,q3.z,q3.w};
#pragma unroll
          for (int i = 0; i < 16; ++i) {
            wv[2*i]   = bflo(qs_[i]);
            wv[2*i+1] = bfhi(qs_[i]);
          }
        }
#pragma unroll
        for (int mm = 0; mm < 4; ++mm) {
          const int m = hf * 4 + mm;
          const float* wm = &wv[mm * 8];
          if (p == 0) {
            float g = xs[m] * s0;
#pragma unroll
            for (int n = 0; n < 8; ++n) accs[n] = fmaf(wm[n], g, accs[n]);
          } else if (p == 1) {
            float a = xs[m];
            float gx = a * s1x, gy = a * s1y, gz = a * s1z;
#pragma unroll
            for (int n = 0; n < 8; ++n) {
              accv[n][0] = fmaf(wm[n], gx, accv[n][0]);
              accv[n][1] = fmaf(wm[n], gy, accv[n][1]);
              accv[n][2] = fmaf(wm[n], gz, accv[n][2]);
            }
          } else if (p == 2) {
            float gx = xv[m][0] * s0, gy = xv[m][1] * s0, gz = xv[m][2] * s0;
#pragma unroll
            for (int n = 0; n < 8; ++n) {
              accv[n][0] = fmaf(wm[n], gx, accv[n][0]);
              accv[n][1] = fmaf(wm[n], gy, accv[n][1]);
              accv[n][2] = fmaf(wm[n], gz, accv[n][2]);
            }
          } else if (p == 3) {
            float dm = (xv[m][0]*s1x + xv[m][1]*s1y + xv[m][2]*s1z) * INV_SQRT3;
#pragma unroll
            for (int n = 0; n < 8; ++n) accs[n] = fmaf(wm[n], dm, accs[n]);
          } else {
            float crx = (xv[m][1]*s1z - xv[m][2]*s1y) * INV_SQRT2;
            float cry = (xv[m][2]*s1x - xv[m][0]*s1z) * INV_SQRT2;
            float crz = (xv[m][0]*s1y - xv[m][1]*s1x) * INV_SQRT2;
#pragma unroll
            for (int n = 0; n < 8; ++n) {
              accv[n][0] = fmaf(wm[n], crx, accv[n][0]);
              accv[n][1] = fmaf(wm[n], cry, accv[n][1]);
              accv[n][2] = fmaf(wm[n], crz, accv[n][2]);
            }
          }
        }
      }
    }

    // ---- epilogue ----
    if (b == 0) {
      float lg = 0.f, lv = 0.f;
#pragma unroll
      for (int n = 0; n < 8; ++n) lg = fmaf(accs[n], qd[dst * 8 + n], lg);
#pragma unroll
      for (int n = 0; n < 8; ++n) {
#pragma unroll
        for (int c = 0; c < 3; ++c)
          lv = fmaf(accv[n][c], qvd[dst * 24 + n * 3 + c], lv);
      }
      float logit = (lg * (1.f / 32.f) +
                     lv * (0.125f * INV_SQRT24) * INV_SQRT3) * 0.25f;
      ex = __expf(logit);
      if (valid) {
        atomicAdd(&z_sum[dst], ex);
        atomicAdd(&cnt[dst], 1.f);
      }
    } else {
      if (valid) {
        float a = sqrtf(ex);
        float* op = out + (size_t)dst * 32;
        const float ss = a * (1.f / 32.f);
        const float sv = a * (0.125f * INV_SQRT24);
#pragma unroll
        for (int n = 0; n < 8; ++n)
          atomicAdd(&op[n], accs[n] * ss);
#pragma unroll
        for (int n = 0; n < 8; ++n) {
          atomicAdd(&op[8 + 3*n + 0], accv[n][0] * sv);
          atomicAdd(&op[8 + 3*n + 1], accv[n][1] * sv);
          atomicAdd(&op[8 + 3*n + 2], accv[n][2] * sv);
        }
      }
    }
  }
}

// ---------------- out[n][i] *= sqrt(max(cnt,1)/z_sum) ----------------
__global__ __launch_bounds__(256) void zscale_kernel(
    const float* __restrict__ z_sum, const float* __restrict__ cnt,
    float* __restrict__ out)
{
  int t = blockIdx.x * blockDim.x + threadIdx.x;
  if (t >= NN * 32) return;
  int n = t >> 5;
  float zs = z_sum[n];
  float s = (zs > 0.f) ? sqrtf(fmaxf(cnt[n], 1.f) / zs) : 0.f;
  out[t] *= s;
}

extern "C" void kernel_launch(void* const* d_in, const int* in_sizes, int n_in,
                              void* d_out, int out_size, void* d_ws, size_t ws_size,
                              hipStream_t stream)
{
  const float* node_attr  = (const float*)d_in[0];
  const int*   edge_index = (const int*)  d_in[1];
  const float* edge_attr  = (const float*)d_in[2];
  const float* edge_sh    = (const float*)d_in[3];
  const float* Wq0 = (const float*)d_in[4];
  const float* Wq1 = (const float*)d_in[5];
  const float* kW1 = (const float*)d_in[6];
  const float* kW2 = (const float*)d_in[7];
  const float* vW1 = (const float*)d_in[8];
  const float* vW2 = (const float*)d_in[9];
  const float* Wd0 = (const float*)d_in[10];
  const float* Wd1 = (const float*)d_in[11];
  float* out = (float*)d_out;

  float* ws = (float*)d_ws;
  float* qd     = ws;                    // 200000
  float* qvd    = qd   + 200000;         // 600000
  float* kW1T   = qvd  + 600000;         // 1024
  float* vW1T   = kW1T + 1024;           // 1024
  unsigned short* afrag = (unsigned short*)(vW1T + 1024);   // 40960 ushorts
  float* z_sum  = (float*)((char*)afrag + 81920);           // 25024
  float* cnt    = z_sum + 25024;         // 25024

  hipMemsetAsync(out, 0, (size_t)out_size * sizeof(float), stream);
  hipMemsetAsync(z_sum, 0, (size_t)(25024 + 25024) * sizeof(float), stream);

  prep_kernel<<<160, 256, 0, stream>>>(kW1, kW2, vW1, vW2, kW1T, vW1T, afrag);
  node_kernel<<<(NN + 255) / 256, 256, 0, stream>>>(
      node_attr, Wq0, Wq1, Wd0, Wd1, qd, qvd);
  edge_kernel<<<(NE + 255) / 256, 256, 0, stream>>>(
      node_attr, edge_index, edge_attr, edge_sh,
      kW1T, vW1T, afrag, qd, qvd, out, z_sum, cnt);
  zscale_kernel<<<(NN * 32 + 255) / 256, 256, 0, stream>>>(z_sum, cnt, out);
}

// Round 5
// 389.963 us; speedup vs baseline: 1.3233x; 1.3233x over previous
//
#include <hip/hip_runtime.h>
#include <math.h>

#define NE 200000
#define NN 25000

static constexpr float INV_SQRT3  = 0.5773502691896258f;
static constexpr float INV_SQRT2  = 0.7071067811865476f;
static constexpr float INV_SQRT8  = 0.3535533905932738f;
static constexpr float INV_SQRT24 = 0.2041241452319315f;

typedef __attribute__((ext_vector_type(8))) short bf16x8;
typedef __attribute__((ext_vector_type(4))) float f32x4;

union U16x8 { uint4 u; bf16x8 v; };

__device__ __forceinline__ unsigned f2bf1(float f) {
  unsigned u = __float_as_uint(f);
  return (u + 0x7FFFu + ((u >> 16) & 1u)) >> 16;
}
__device__ __forceinline__ unsigned packbf(float a, float b) {
  return f2bf1(a) | (f2bf1(b) << 16);
}
__device__ __forceinline__ float bflo(unsigned u) { return __uint_as_float(u << 16); }
__device__ __forceinline__ float bfhi(unsigned u) { return __uint_as_float(u & 0xFFFF0000u); }

// ---------------- fused prep: W1T transpose + W2 A-frags + node q's + dst histogram ----
__global__ __launch_bounds__(256) void prep_kernel(
    const float* __restrict__ kW1, const float* __restrict__ kW2,
    const float* __restrict__ vW1, const float* __restrict__ vW2,
    const float* __restrict__ node_attr,
    const float* __restrict__ Wq0, const float* __restrict__ Wq1,
    const float* __restrict__ Wd0, const float* __restrict__ Wd1,
    const int*   __restrict__ edge_index,
    float* __restrict__ kW1T, float* __restrict__ vW1T,
    unsigned short* __restrict__ afrag,
    float* __restrict__ qd, float* __restrict__ qvd,
    int* __restrict__ hist)
{
  int t = blockIdx.x * blockDim.x + threadIdx.x;   // 40960 threads
  if (t < 1024) {
    int j = t >> 6;
    int r = t & 63;
    kW1T[r * 16 + j] = kW1[t];
    vW1T[r * 16 + j] = vW1[t];
  }
  if (t < 40960) {
    int j    = t & 7;
    int lane = (t >> 3) & 63;
    int kk   = (t >> 9) & 1;
    int ot   = (t >> 10) & 1;
    int ci   = t >> 11;
    int b    = ci / 10;
    int rem  = ci - b * 10;
    int p    = rem >> 1;
    int hf   = rem & 1;
    int r    = kk * 32 + ((lane >> 4) << 3) + j;
    int o    = p * 64 + hf * 32 + ot * 16 + (lane & 15);
    const float* W = b ? vW2 : kW2;
    afrag[t] = (unsigned short)f2bf1(W[r * 320 + o]);
  }
  // histogram of dst: 5 edges per thread (40960*5 >= 200000)
#pragma unroll
  for (int i = 0; i < 5; ++i) {
    int e = t * 5 + i;
    if (e < NE) atomicAdd(&hist[edge_index[NE + e]], 1);
  }
  // per-node q precompute
  if (t < NN) {
    int n = t;
    float ns[8], nv[24];
#pragma unroll
    for (int i = 0; i < 8; ++i)  ns[i] = node_attr[n * 32 + i];
#pragma unroll
    for (int i = 0; i < 24; ++i) nv[i] = node_attr[n * 32 + 8 + i];
    float qs[8];
#pragma unroll
    for (int m = 0; m < 8; ++m) {
      float a = 0.f;
#pragma unroll
      for (int i = 0; i < 8; ++i) a = fmaf(ns[i], Wq0[i * 8 + m], a);
      qs[m] = a * INV_SQRT8;
    }
#pragma unroll
    for (int k = 0; k < 8; ++k) {
      float a = 0.f;
#pragma unroll
      for (int m = 0; m < 8; ++m) a = fmaf(qs[m], Wd0[m * 8 + k], a);
      qd[n * 8 + k] = a;
    }
    float qv[24];
#pragma unroll
    for (int k = 0; k < 8; ++k) {
#pragma unroll
      for (int c = 0; c < 3; ++c) {
        float a = 0.f;
#pragma unroll
        for (int m = 0; m < 8; ++m) a = fmaf(nv[m * 3 + c], Wq1[m * 8 + k], a);
        qv[k * 3 + c] = a * INV_SQRT8;
      }
    }
#pragma unroll
    for (int k = 0; k < 8; ++k) {
#pragma unroll
      for (int c = 0; c < 3; ++c) {
        float a = 0.f;
#pragma unroll
        for (int m = 0; m < 8; ++m) a = fmaf(qv[m * 3 + c], Wd1[m * 8 + k], a);
        qvd[n * 24 + k * 3 + c] = a;
      }
    }
  }
}

// ---------------- exclusive scan of hist -> off (NN+1) and cursor copy ----------------
__global__ __launch_bounds__(1024) void scan_kernel(
    const int* __restrict__ hist, int* __restrict__ off, int* __restrict__ cursor)
{
  __shared__ int buf[1024];
  __shared__ int carry;
  const int tid = threadIdx.x;
  if (tid == 0) carry = 0;
  __syncthreads();
  for (int base = 0; base < NN; base += 1024) {
    int i = base + tid;
    int v = (i < NN) ? hist[i] : 0;
    buf[tid] = v;
    __syncthreads();
#pragma unroll
    for (int s = 1; s < 1024; s <<= 1) {
      int t = (tid >= s) ? buf[tid - s] : 0;
      __syncthreads();
      buf[tid] += t;
      __syncthreads();
    }
    int incl = buf[tid];
    int c = carry;
    if (i < NN) {
      int ex = c + incl - v;
      off[i] = ex;
      cursor[i] = ex;
    }
    __syncthreads();
    if (tid == 1023) carry = c + incl;
    __syncthreads();
  }
  if (tid == 0) off[NN] = carry;
}

// ---------------- main edge pass (MFMA) ----------------
// Writes ex and sqrt(ex)-scaled value rows into CSR slot pos = cursor[dst]++.
// Zero fp32 atomics (R4's fused out-atomics cost 212 MB of HBM writes).
__global__ __launch_bounds__(256) void edge_kernel(
    const float* __restrict__ node_attr,
    const int*   __restrict__ edge_index,
    const float* __restrict__ edge_attr,
    const float* __restrict__ edge_sh,
    const float* __restrict__ kW1T, const float* __restrict__ vW1T,
    const unsigned short* __restrict__ afrag,
    const float* __restrict__ qd,   const float* __restrict__ qvd,
    int* __restrict__ cursor,
    float* __restrict__ exo, float* __restrict__ wout)
{
  __shared__ unsigned char smem[65536];
  float* sW1 = (float*)smem;                              // 8 KiB
  const int tid  = threadIdx.x;
  const int lane = tid & 63;
  const int wave = tid >> 6;
  const int l15  = lane & 15;
  const int quad = lane >> 4;
  unsigned char* sh  = smem + 8192  + wave * 9216;        // 64 x 144 B
  unsigned char* swp = smem + 45056 + wave * 5120;        // 64 x 80 B

  ((float4*)sW1)[tid]       = ((const float4*)kW1T)[tid];
  ((float4*)sW1)[256 + tid] = ((const float4*)vW1T)[tid];
  __syncthreads();

  const int e = blockIdx.x * 256 + tid;
  const bool valid = (e < NE);
  const int el  = valid ? e : (NE - 1);
  const int src = edge_index[el];
  const int dst = edge_index[NE + el];

  int pos = 0;
  if (valid) pos = atomicAdd(&cursor[dst], 1);

  const float s0  = edge_sh[el * 4 + 0];
  const float s1x = edge_sh[el * 4 + 1];
  const float s1y = edge_sh[el * 4 + 2];
  const float s1z = edge_sh[el * 4 + 3];

  float ea[16];
  {
    const float4* ea4 = (const float4*)(edge_attr + (size_t)el * 16);
#pragma unroll
    for (int i = 0; i < 4; ++i) {
      float4 v = ea4[i];
      ea[4*i+0] = v.x; ea[4*i+1] = v.y; ea[4*i+2] = v.z; ea[4*i+3] = v.w;
    }
  }
  float xs[8], xv[8][3];
  {
    const float4* na4 = (const float4*)(node_attr + (size_t)src * 32);
    float tmp[32];
#pragma unroll
    for (int i = 0; i < 8; ++i) {
      float4 v = na4[i];
      tmp[4*i+0] = v.x; tmp[4*i+1] = v.y; tmp[4*i+2] = v.z; tmp[4*i+3] = v.w;
    }
#pragma unroll
    for (int m = 0; m < 8; ++m) xs[m] = tmp[m];
#pragma unroll
    for (int m = 0; m < 8; ++m) {
      xv[m][0] = tmp[8 + 3*m + 0];
      xv[m][1] = tmp[8 + 3*m + 1];
      xv[m][2] = tmp[8 + 3*m + 2];
    }
  }

  const uint4* AF = (const uint4*)afrag;
  float ex = 0.f;

#pragma unroll 1
  for (int b = 0; b < 2; ++b) {
    const float* W1base = sW1 + b * 1024;
    float h[64];
#pragma unroll
    for (int r = 0; r < 64; ++r) {
      const float4* rp = (const float4*)(W1base + r * 16);
      float4 x0 = rp[0], x1 = rp[1], x2 = rp[2], x3 = rp[3];
      float a0 = 0.f, a1 = 0.f;
      a0 = fmaf(ea[ 0], x0.x, a0); a0 = fmaf(ea[ 1], x0.y, a0);
      a0 = fmaf(ea[ 2], x0.z, a0); a0 = fmaf(ea[ 3], x0.w, a0);
      a1 = fmaf(ea[ 4], x1.x, a1); a1 = fmaf(ea[ 5], x1.y, a1);
      a1 = fmaf(ea[ 6], x1.z, a1); a1 = fmaf(ea[ 7], x1.w, a1);
      a0 = fmaf(ea[ 8], x2.x, a0); a0 = fmaf(ea[ 9], x2.y, a0);
      a0 = fmaf(ea[10], x2.z, a0); a0 = fmaf(ea[11], x2.w, a0);
      a1 = fmaf(ea[12], x3.x, a1); a1 = fmaf(ea[13], x3.y, a1);
      a1 = fmaf(ea[14], x3.z, a1); a1 = fmaf(ea[15], x3.w, a1);
      float a = (a0 + a1) * 0.25f;
      h[r] = a / (1.f + __expf(-a));
    }

    {
      unsigned char* myrow = sh + lane * 144;
#pragma unroll
      for (int i = 0; i < 8; ++i) {
        uint4 pk;
        pk.x = packbf(h[8*i+0], h[8*i+1]);
        pk.y = packbf(h[8*i+2], h[8*i+3]);
        pk.z = packbf(h[8*i+4], h[8*i+5]);
        pk.w = packbf(h[8*i+6], h[8*i+7]);
        *(uint4*)(myrow + i * 16) = pk;
      }
    }

    bf16x8 B[4][2];
#pragma unroll
    for (int et = 0; et < 4; ++et) {
#pragma unroll
      for (int kk = 0; kk < 2; ++kk) {
        U16x8 cv;
        cv.u = *(const uint4*)(sh + (et*16 + l15) * 144 + kk * 64 + quad * 16);
        B[et][kk] = cv.v;
      }
    }

    float accs[8];
    float accv[8][3];
#pragma unroll
    for (int n = 0; n < 8; ++n) {
      accs[n] = 0.f;
      accv[n][0] = 0.f; accv[n][1] = 0.f; accv[n][2] = 0.f;
    }

#pragma unroll
    for (int p = 0; p < 5; ++p) {
#pragma unroll
      for (int hf = 0; hf < 2; ++hf) {
        const int ci = b * 10 + p * 2 + hf;
        U16x8 a00, a01, a10, a11;
        a00.u = AF[(ci*4 + 0) * 64 + lane];
        a01.u = AF[(ci*4 + 1) * 64 + lane];
        a10.u = AF[(ci*4 + 2) * 64 + lane];
        a11.u = AF[(ci*4 + 3) * 64 + lane];

#pragma unroll
        for (int et = 0; et < 4; ++et) {
          f32x4 c0 = {0.f, 0.f, 0.f, 0.f};
          f32x4 c1 = {0.f, 0.f, 0.f, 0.f};
          c0 = __builtin_amdgcn_mfma_f32_16x16x32_bf16(a00.v, B[et][0], c0, 0, 0, 0);
          c0 = __builtin_amdgcn_mfma_f32_16x16x32_bf16(a01.v, B[et][1], c0, 0, 0, 0);
          c1 = __builtin_amdgcn_mfma_f32_16x16x32_bf16(a10.v, B[et][0], c1, 0, 0, 0);
          c1 = __builtin_amdgcn_mfma_f32_16x16x32_bf16(a11.v, B[et][1], c1, 0, 0, 0);
          unsigned char* wrow = swp + (et*16 + l15) * 80;
          uint2 p0; p0.x = packbf(c0.x, c0.y); p0.y = packbf(c0.z, c0.w);
          uint2 p1; p1.x = packbf(c1.x, c1.y); p1.y = packbf(c1.z, c1.w);
          *(uint2*)(wrow + quad * 8)      = p0;
          *(uint2*)(wrow + 32 + quad * 8) = p1;
        }

        float wv[32];
        {
          const uint4* wr = (const uint4*)(swp + (size_t)lane * 80);
          uint4 q0 = wr[0], q1 = wr[1], q2 = wr[2], q3 = wr[3];
          unsigned qs_[16] = {q0.x,q0.y,q0.z,q0.w, q1.x,q1.y,q1.z,q1.w,
                              q2.x,q2.y,q2.z,q2.w, q3.x,q3.y,q3.z,q3.w};
#pragma unroll
          for (int i = 0; i < 16; ++i) {
            wv[2*i]   = bflo(qs_[i]);
            wv[2*i+1] = bfhi(qs_[i]);
          }
        }
#pragma unroll
        for (int mm = 0; mm < 4; ++mm) {
          const int m = hf * 4 + mm;
          const float* wm = &wv[mm * 8];
          if (p == 0) {
            float g = xs[m] * s0;
#pragma unroll
            for (int n = 0; n < 8; ++n) accs[n] = fmaf(wm[n], g, accs[n]);
          } else if (p == 1) {
            float a = xs[m];
            float gx = a * s1x, gy = a * s1y, gz = a * s1z;
#pragma unroll
            for (int n = 0; n < 8; ++n) {
              accv[n][0] = fmaf(wm[n], gx, accv[n][0]);
              accv[n][1] = fmaf(wm[n], gy, accv[n][1]);
              accv[n][2] = fmaf(wm[n], gz, accv[n][2]);
            }
          } else if (p == 2) {
            float gx = xv[m][0] * s0, gy = xv[m][1] * s0, gz = xv[m][2] * s0;
#pragma unroll
            for (int n = 0; n < 8; ++n) {
              accv[n][0] = fmaf(wm[n], gx, accv[n][0]);
              accv[n][1] = fmaf(wm[n], gy, accv[n][1]);
              accv[n][2] = fmaf(wm[n], gz, accv[n][2]);
            }
          } else if (p == 3) {
            float dm = (xv[m][0]*s1x + xv[m][1]*s1y + xv[m][2]*s1z) * INV_SQRT3;
#pragma unroll
            for (int n = 0; n < 8; ++n) accs[n] = fmaf(wm[n], dm, accs[n]);
          } else {
            float crx = (xv[m][1]*s1z - xv[m][2]*s1y) * INV_SQRT2;
            float cry = (xv[m][2]*s1x - xv[m][0]*s1z) * INV_SQRT2;
            float crz = (xv[m][0]*s1y - xv[m][1]*s1x) * INV_SQRT2;
#pragma unroll
            for (int n = 0; n < 8; ++n) {
              accv[n][0] = fmaf(wm[n], crx, accv[n][0]);
              accv[n][1] = fmaf(wm[n], cry, accv[n][1]);
              accv[n][2] = fmaf(wm[n], crz, accv[n][2]);
            }
          }
        }
      }
    }

    if (b == 0) {
      float lg = 0.f, lv = 0.f;
#pragma unroll
      for (int n = 0; n < 8; ++n) lg = fmaf(accs[n], qd[dst * 8 + n], lg);
#pragma unroll
      for (int n = 0; n < 8; ++n) {
#pragma unroll
        for (int c = 0; c < 3; ++c)
          lv = fmaf(accv[n][c], qvd[dst * 24 + n * 3 + c], lv);
      }
      float logit = (lg * (1.f / 32.f) +
                     lv * (0.125f * INV_SQRT24) * INV_SQRT3) * 0.25f;
      ex = __expf(logit);
      if (valid) exo[pos] = ex;
    } else {
      if (valid) {
        float a = sqrtf(ex);
        const float ss = a * (1.f / 32.f);
        const float sv = a * (0.125f * INV_SQRT24);
        float4* v4 = (float4*)(wout + (size_t)pos * 32);
        float4 o;
        o.x = accs[0] * ss; o.y = accs[1] * ss;
        o.z = accs[2] * ss; o.w = accs[3] * ss;
        v4[0] = o;
        o.x = accs[4] * ss; o.y = accs[5] * ss;
        o.z = accs[6] * ss; o.w = accs[7] * ss;
        v4[1] = o;
        float vvv[24];
#pragma unroll
        for (int n = 0; n < 8; ++n) {
          vvv[3*n+0] = accv[n][0] * sv;
          vvv[3*n+1] = accv[n][1] * sv;
          vvv[3*n+2] = accv[n][2] * sv;
        }
#pragma unroll
        for (int i = 0; i < 6; ++i) {
          float4 t;
          t.x = vvv[4*i+0]; t.y = vvv[4*i+1]; t.z = vvv[4*i+2]; t.w = vvv[4*i+3];
          v4[2 + i] = t;
        }
      }
    }
  }
}

// ---------------- gather: one wave per node over its CSR segment ----------------
__global__ __launch_bounds__(256) void gather_kernel(
    const int* __restrict__ off,
    const float* __restrict__ exo,
    const float* __restrict__ wout,
    float* __restrict__ out)
{
  const int tid  = threadIdx.x;
  const int wave = tid >> 6;
  const int lane = tid & 63;
  const int n = blockIdx.x * 4 + wave;
  if (n >= NN) return;
  const int start = off[n];
  const int end   = off[n + 1];
  const int cnt   = end - start;

  // z = sum of ex over segment
  float zp = 0.f;
  for (int j = start + lane; j < end; j += 64) zp += exo[j];
#pragma unroll
  for (int s = 32; s >= 1; s >>= 1) zp += __shfl_xor(zp, s, 64);

  // acc over w rows: lanes 0-31 even rows' elems, lanes 32-63 odd rows
  const int l = lane & 31;
  const int hh = lane >> 5;
  float acc = 0.f;
  for (int j = start + hh; j < end; j += 2)
    acc += wout[(size_t)j * 32 + l];
  acc += __shfl_xor(acc, 32, 64);

  if (lane < 32) {
    float s = (cnt > 0 && zp > 0.f) ? sqrtf((float)cnt / zp) : 0.f;
    out[(size_t)n * 32 + l] = acc * s;
  }
}

extern "C" void kernel_launch(void* const* d_in, const int* in_sizes, int n_in,
                              void* d_out, int out_size, void* d_ws, size_t ws_size,
                              hipStream_t stream)
{
  const float* node_attr  = (const float*)d_in[0];
  const int*   edge_index = (const int*)  d_in[1];
  const float* edge_attr  = (const float*)d_in[2];
  const float* edge_sh    = (const float*)d_in[3];
  const float* Wq0 = (const float*)d_in[4];
  const float* Wq1 = (const float*)d_in[5];
  const float* kW1 = (const float*)d_in[6];
  const float* kW2 = (const float*)d_in[7];
  const float* vW1 = (const float*)d_in[8];
  const float* vW2 = (const float*)d_in[9];
  const float* Wd0 = (const float*)d_in[10];
  const float* Wd1 = (const float*)d_in[11];
  float* out = (float*)d_out;

  float* ws = (float*)d_ws;
  float* qd     = ws;                    // 200000
  float* qvd    = qd   + 200000;         // 600000
  float* kW1T   = qvd  + 600000;         // 1024
  float* vW1T   = kW1T + 1024;           // 1024
  unsigned short* afrag = (unsigned short*)(vW1T + 1024);   // 40960 ushorts
  int* hist   = (int*)((char*)afrag + 81920);               // 25024
  int* off    = hist + 25024;                               // 25056 (NN+1)
  int* cursor = off  + 25056;                               // 25024
  float* exo  = (float*)(cursor + 25024);                   // 200000
  float* wout = exo + 200000;                               // 6400000

  hipMemsetAsync(hist, 0, 25024 * sizeof(int), stream);

  prep_kernel<<<160, 256, 0, stream>>>(
      kW1, kW2, vW1, vW2, node_attr, Wq0, Wq1, Wd0, Wd1, edge_index,
      kW1T, vW1T, afrag, qd, qvd, hist);
  scan_kernel<<<1, 1024, 0, stream>>>(hist, off, cursor);
  edge_kernel<<<(NE + 255) / 256, 256, 0, stream>>>(
      node_attr, edge_index, edge_attr, edge_sh,
      kW1T, vW1T, afrag, qd, qvd, cursor, exo, wout);
  gather_kernel<<<(NN + 3) / 4, 256, 0, stream>>>(off, exo, wout, out);
}

// Round 6
// 377.344 us; speedup vs baseline: 1.3675x; 1.0334x over previous
//
#include <hip/hip_runtime.h>
#include <math.h>

#define NE 200000
#define NN 25000

static constexpr float INV_SQRT3  = 0.5773502691896258f;
static constexpr float INV_SQRT2  = 0.7071067811865476f;
static constexpr float INV_SQRT8  = 0.3535533905932738f;
static constexpr float INV_SQRT24 = 0.2041241452319315f;

typedef __attribute__((ext_vector_type(8))) short bf16x8;
typedef __attribute__((ext_vector_type(4))) float f32x4;

union U16x8 { uint4 u; bf16x8 v; };

__device__ __forceinline__ unsigned f2bf1(float f) {
  unsigned u = __float_as_uint(f);
  return (u + 0x7FFFu + ((u >> 16) & 1u)) >> 16;
}
__device__ __forceinline__ unsigned packbf(float a, float b) {
  return f2bf1(a) | (f2bf1(b) << 16);
}
__device__ __forceinline__ float bflo(unsigned u) { return __uint_as_float(u << 16); }
__device__ __forceinline__ float bfhi(unsigned u) { return __uint_as_float(u & 0xFFFF0000u); }

// ---------------- fused prep: W1T transpose + W2 A-frags + node q's + dst histogram ----
__global__ __launch_bounds__(256) void prep_kernel(
    const float* __restrict__ kW1, const float* __restrict__ kW2,
    const float* __restrict__ vW1, const float* __restrict__ vW2,
    const float* __restrict__ node_attr,
    const float* __restrict__ Wq0, const float* __restrict__ Wq1,
    const float* __restrict__ Wd0, const float* __restrict__ Wd1,
    const int*   __restrict__ edge_index,
    float* __restrict__ kW1T, float* __restrict__ vW1T,
    unsigned short* __restrict__ afrag,
    float* __restrict__ qd, float* __restrict__ qvd,
    int* __restrict__ hist)
{
  int t = blockIdx.x * blockDim.x + threadIdx.x;   // 40960 threads
  if (t < 1024) {
    int j = t >> 6;
    int r = t & 63;
    kW1T[r * 16 + j] = kW1[t];
    vW1T[r * 16 + j] = vW1[t];
  }
  if (t < 40960) {
    int j    = t & 7;
    int lane = (t >> 3) & 63;
    int kk   = (t >> 9) & 1;
    int ot   = (t >> 10) & 1;
    int ci   = t >> 11;
    int b    = ci / 10;
    int rem  = ci - b * 10;
    int p    = rem >> 1;
    int hf   = rem & 1;
    int r    = kk * 32 + ((lane >> 4) << 3) + j;
    int o    = p * 64 + hf * 32 + ot * 16 + (lane & 15);
    const float* W = b ? vW2 : kW2;
    afrag[t] = (unsigned short)f2bf1(W[r * 320 + o]);
  }
#pragma unroll
  for (int i = 0; i < 5; ++i) {
    int e = t * 5 + i;
    if (e < NE) atomicAdd(&hist[edge_index[NE + e]], 1);
  }
  if (t < NN) {
    int n = t;
    float ns[8], nv[24];
#pragma unroll
    for (int i = 0; i < 8; ++i)  ns[i] = node_attr[n * 32 + i];
#pragma unroll
    for (int i = 0; i < 24; ++i) nv[i] = node_attr[n * 32 + 8 + i];
    float qs[8];
#pragma unroll
    for (int m = 0; m < 8; ++m) {
      float a = 0.f;
#pragma unroll
      for (int i = 0; i < 8; ++i) a = fmaf(ns[i], Wq0[i * 8 + m], a);
      qs[m] = a * INV_SQRT8;
    }
#pragma unroll
    for (int k = 0; k < 8; ++k) {
      float a = 0.f;
#pragma unroll
      for (int m = 0; m < 8; ++m) a = fmaf(qs[m], Wd0[m * 8 + k], a);
      qd[n * 8 + k] = a;
    }
    float qv[24];
#pragma unroll
    for (int k = 0; k < 8; ++k) {
#pragma unroll
      for (int c = 0; c < 3; ++c) {
        float a = 0.f;
#pragma unroll
        for (int m = 0; m < 8; ++m) a = fmaf(nv[m * 3 + c], Wq1[m * 8 + k], a);
        qv[k * 3 + c] = a * INV_SQRT8;
      }
    }
#pragma unroll
    for (int k = 0; k < 8; ++k) {
#pragma unroll
      for (int c = 0; c < 3; ++c) {
        float a = 0.f;
#pragma unroll
        for (int m = 0; m < 8; ++m) a = fmaf(qv[m * 3 + c], Wd1[m * 8 + k], a);
        qvd[n * 24 + k * 3 + c] = a;
      }
    }
  }
}

// ---------------- chunked shfl scan: hist -> off (NN+1), cursor ----------------
// Each thread serially scans 25 contiguous elems; wave shfl-scan + 16-wave
// combine; 2 barriers total (R5's ladder scan had 250 barrier rounds).
__global__ __launch_bounds__(1024) void scan_kernel(
    const int* __restrict__ hist, int* __restrict__ off, int* __restrict__ cursor)
{
  __shared__ int wsum[16];
  const int tid  = threadIdx.x;
  const int lane = tid & 63;
  const int wv   = tid >> 6;
  const int base = tid * 25;
  int loc[25];
  int s = 0;
#pragma unroll
  for (int i = 0; i < 25; ++i) {
    int idx = base + i;
    int v = (idx < NN) ? hist[idx] : 0;
    loc[i] = s;
    s += v;
  }
  int incl = s;
#pragma unroll
  for (int d = 1; d < 64; d <<= 1) {
    int t = __shfl_up(incl, d, 64);
    if (lane >= d) incl += t;
  }
  int wexcl = incl - s;
  if (lane == 63) wsum[wv] = incl;
  __syncthreads();
  if (wv == 0 && lane < 16) {
    int v = wsum[lane];
    int inc2 = v;
#pragma unroll
    for (int d = 1; d < 16; d <<= 1) {
      int t = __shfl_up(inc2, d, 64);
      if (lane >= d) inc2 += t;
    }
    wsum[lane] = inc2 - v;
  }
  __syncthreads();
  int tbase = wsum[wv] + wexcl;
#pragma unroll
  for (int i = 0; i < 25; ++i) {
    int idx = base + i;
    if (idx < NN) { int e = tbase + loc[i]; off[idx] = e; cursor[idx] = e; }
  }
  if (tid == 1023) off[NN] = tbase + s;
}

// ---------------- main edge pass (MFMA, CSR output) ----------------
// Register-pressure discipline (R5 spilled at the 256-VGPR cap):
//  - h computed in groups of 8 and packed straight to LDS (never a fp32[64])
//  - ea re-loaded per branch instead of held across both
__global__ __launch_bounds__(256) void edge_kernel(
    const float* __restrict__ node_attr,
    const int*   __restrict__ edge_index,
    const float* __restrict__ edge_attr,
    const float* __restrict__ edge_sh,
    const float* __restrict__ kW1T, const float* __restrict__ vW1T,
    const unsigned short* __restrict__ afrag,
    const float* __restrict__ qd,   const float* __restrict__ qvd,
    int* __restrict__ cursor,
    float* __restrict__ exo, float* __restrict__ wout)
{
  __shared__ unsigned char smem[65536];
  float* sW1 = (float*)smem;                              // 8 KiB
  const int tid  = threadIdx.x;
  const int lane = tid & 63;
  const int wave = tid >> 6;
  const int l15  = lane & 15;
  const int quad = lane >> 4;
  unsigned char* sh  = smem + 8192  + wave * 9216;        // 64 x 144 B
  unsigned char* swp = smem + 45056 + wave * 5120;        // 64 x 80 B

  ((float4*)sW1)[tid]       = ((const float4*)kW1T)[tid];
  ((float4*)sW1)[256 + tid] = ((const float4*)vW1T)[tid];
  __syncthreads();

  const int e = blockIdx.x * 256 + tid;
  const bool valid = (e < NE);
  const int el  = valid ? e : (NE - 1);
  const int src = edge_index[el];
  const int dst = edge_index[NE + el];

  int pos = 0;
  if (valid) pos = atomicAdd(&cursor[dst], 1);

  const float s0  = edge_sh[el * 4 + 0];
  const float s1x = edge_sh[el * 4 + 1];
  const float s1y = edge_sh[el * 4 + 2];
  const float s1z = edge_sh[el * 4 + 3];

  float xs[8], xv[8][3];
  {
    const float4* na4 = (const float4*)(node_attr + (size_t)src * 32);
    float tmp[32];
#pragma unroll
    for (int i = 0; i < 8; ++i) {
      float4 v = na4[i];
      tmp[4*i+0] = v.x; tmp[4*i+1] = v.y; tmp[4*i+2] = v.z; tmp[4*i+3] = v.w;
    }
#pragma unroll
    for (int m = 0; m < 8; ++m) xs[m] = tmp[m];
#pragma unroll
    for (int m = 0; m < 8; ++m) {
      xv[m][0] = tmp[8 + 3*m + 0];
      xv[m][1] = tmp[8 + 3*m + 1];
      xv[m][2] = tmp[8 + 3*m + 2];
    }
  }

  const uint4* AF = (const uint4*)afrag;
  float ex = 0.f;

#pragma unroll 1
  for (int b = 0; b < 2; ++b) {
    // ---- h = silu(ea @ W1 / 4), computed 8 rows at a time, packed to LDS ----
    {
      float ea[16];
      const float4* ea4 = (const float4*)(edge_attr + (size_t)el * 16);
#pragma unroll
      for (int i = 0; i < 4; ++i) {
        float4 v = ea4[i];
        ea[4*i+0] = v.x; ea[4*i+1] = v.y; ea[4*i+2] = v.z; ea[4*i+3] = v.w;
      }
      const float* W1base = sW1 + b * 1024;
      unsigned char* myrow = sh + lane * 144;
#pragma unroll 1
      for (int g = 0; g < 8; ++g) {
        float hg[8];
#pragma unroll
        for (int rr = 0; rr < 8; ++rr) {
          const float4* rp = (const float4*)(W1base + (g * 8 + rr) * 16);
          float4 x0 = rp[0], x1 = rp[1], x2 = rp[2], x3 = rp[3];
          float a0 = 0.f, a1 = 0.f;
          a0 = fmaf(ea[ 0], x0.x, a0); a0 = fmaf(ea[ 1], x0.y, a0);
          a0 = fmaf(ea[ 2], x0.z, a0); a0 = fmaf(ea[ 3], x0.w, a0);
          a1 = fmaf(ea[ 4], x1.x, a1); a1 = fmaf(ea[ 5], x1.y, a1);
          a1 = fmaf(ea[ 6], x1.z, a1); a1 = fmaf(ea[ 7], x1.w, a1);
          a0 = fmaf(ea[ 8], x2.x, a0); a0 = fmaf(ea[ 9], x2.y, a0);
          a0 = fmaf(ea[10], x2.z, a0); a0 = fmaf(ea[11], x2.w, a0);
          a1 = fmaf(ea[12], x3.x, a1); a1 = fmaf(ea[13], x3.y, a1);
          a1 = fmaf(ea[14], x3.z, a1); a1 = fmaf(ea[15], x3.w, a1);
          float a = (a0 + a1) * 0.25f;
          hg[rr] = a / (1.f + __expf(-a));
        }
        uint4 pk;
        pk.x = packbf(hg[0], hg[1]);
        pk.y = packbf(hg[2], hg[3]);
        pk.z = packbf(hg[4], hg[5]);
        pk.w = packbf(hg[6], hg[7]);
        *(uint4*)(myrow + g * 16) = pk;
      }
    }

    // ---- B-fragments (H), read once, reused for all 10 chunks ----
    bf16x8 B[4][2];
#pragma unroll
    for (int et = 0; et < 4; ++et) {
#pragma unroll
      for (int kk = 0; kk < 2; ++kk) {
        U16x8 cv;
        cv.u = *(const uint4*)(sh + (et*16 + l15) * 144 + kk * 64 + quad * 16);
        B[et][kk] = cv.v;
      }
    }

    float accs[8];
    float accv[8][3];
#pragma unroll
    for (int n = 0; n < 8; ++n) {
      accs[n] = 0.f;
      accv[n][0] = 0.f; accv[n][1] = 0.f; accv[n][2] = 0.f;
    }

#pragma unroll
    for (int p = 0; p < 5; ++p) {
#pragma unroll
      for (int hf = 0; hf < 2; ++hf) {
        const int ci = b * 10 + p * 2 + hf;
        U16x8 a00, a01, a10, a11;
        a00.u = AF[(ci*4 + 0) * 64 + lane];
        a01.u = AF[(ci*4 + 1) * 64 + lane];
        a10.u = AF[(ci*4 + 2) * 64 + lane];
        a11.u = AF[(ci*4 + 3) * 64 + lane];

#pragma unroll
        for (int et = 0; et < 4; ++et) {
          f32x4 c0 = {0.f, 0.f, 0.f, 0.f};
          f32x4 c1 = {0.f, 0.f, 0.f, 0.f};
          c0 = __builtin_amdgcn_mfma_f32_16x16x32_bf16(a00.v, B[et][0], c0, 0, 0, 0);
          c0 = __builtin_amdgcn_mfma_f32_16x16x32_bf16(a01.v, B[et][1], c0, 0, 0, 0);
          c1 = __builtin_amdgcn_mfma_f32_16x16x32_bf16(a10.v, B[et][0], c1, 0, 0, 0);
          c1 = __builtin_amdgcn_mfma_f32_16x16x32_bf16(a11.v, B[et][1], c1, 0, 0, 0);
          unsigned char* wrow = swp + (et*16 + l15) * 80;
          uint2 p0; p0.x = packbf(c0.x, c0.y); p0.y = packbf(c0.z, c0.w);
          uint2 p1; p1.x = packbf(c1.x, c1.y); p1.y = packbf(c1.z, c1.w);
          *(uint2*)(wrow + quad * 8)      = p0;
          *(uint2*)(wrow + 32 + quad * 8) = p1;
        }

        float wv[32];
        {
          const uint4* wr = (const uint4*)(swp + (size_t)lane * 80);
          uint4 q0 = wr[0], q1 = wr[1], q2 = wr[2], q3 = wr[3];
          unsigned qs_[16] = {q0.x,q0.y,q0.z,q0.w, q1.x,q1.y,q1.z,q1.w,
                              q2.x,q2.y,q2.z,q2.w, q3.x,q3.y,q3.z,q3.w};
#pragma unroll
          for (int i = 0; i < 16; ++i) {
            wv[2*i]   = bflo(qs_[i]);
            wv[2*i+1] = bfhi(qs_[i]);
          }
        }
#pragma unroll
        for (int mm = 0; mm < 4; ++mm) {
          const int m = hf * 4 + mm;
          const float* wm = &wv[mm * 8];
          if (p == 0) {
            float g = xs[m] * s0;
#pragma unroll
            for (int n = 0; n < 8; ++n) accs[n] = fmaf(wm[n], g, accs[n]);
          } else if (p == 1) {
            float a = xs[m];
            float gx = a * s1x, gy = a * s1y, gz = a * s1z;
#pragma unroll
            for (int n = 0; n < 8; ++n) {
              accv[n][0] = fmaf(wm[n], gx, accv[n][0]);
              accv[n][1] = fmaf(wm[n], gy, accv[n][1]);
              accv[n][2] = fmaf(wm[n], gz, accv[n][2]);
            }
          } else if (p == 2) {
            float gx = xv[m][0] * s0, gy = xv[m][1] * s0, gz = xv[m][2] * s0;
#pragma unroll
            for (int n = 0; n < 8; ++n) {
              accv[n][0] = fmaf(wm[n], gx, accv[n][0]);
              accv[n][1] = fmaf(wm[n], gy, accv[n][1]);
              accv[n][2] = fmaf(wm[n], gz, accv[n][2]);
            }
          } else if (p == 3) {
            float dm = (xv[m][0]*s1x + xv[m][1]*s1y + xv[m][2]*s1z) * INV_SQRT3;
#pragma unroll
            for (int n = 0; n < 8; ++n) accs[n] = fmaf(wm[n], dm, accs[n]);
          } else {
            float crx = (xv[m][1]*s1z - xv[m][2]*s1y) * INV_SQRT2;
            float cry = (xv[m][2]*s1x - xv[m][0]*s1z) * INV_SQRT2;
            float crz = (xv[m][0]*s1y - xv[m][1]*s1x) * INV_SQRT2;
#pragma unroll
            for (int n = 0; n < 8; ++n) {
              accv[n][0] = fmaf(wm[n], crx, accv[n][0]);
              accv[n][1] = fmaf(wm[n], cry, accv[n][1]);
              accv[n][2] = fmaf(wm[n], crz, accv[n][2]);
            }
          }
        }
      }
    }

    if (b == 0) {
      float lg = 0.f, lv = 0.f;
#pragma unroll
      for (int n = 0; n < 8; ++n) lg = fmaf(accs[n], qd[dst * 8 + n], lg);
#pragma unroll
      for (int n = 0; n < 8; ++n) {
#pragma unroll
        for (int c = 0; c < 3; ++c)
          lv = fmaf(accv[n][c], qvd[dst * 24 + n * 3 + c], lv);
      }
      float logit = (lg * (1.f / 32.f) +
                     lv * (0.125f * INV_SQRT24) * INV_SQRT3) * 0.25f;
      ex = __expf(logit);
      if (valid) exo[pos] = ex;
    } else {
      if (valid) {
        float a = sqrtf(ex);
        const float ss = a * (1.f / 32.f);
        const float sv = a * (0.125f * INV_SQRT24);
        float4* v4 = (float4*)(wout + (size_t)pos * 32);
        float4 o;
        o.x = accs[0] * ss; o.y = accs[1] * ss;
        o.z = accs[2] * ss; o.w = accs[3] * ss;
        v4[0] = o;
        o.x = accs[4] * ss; o.y = accs[5] * ss;
        o.z = accs[6] * ss; o.w = accs[7] * ss;
        v4[1] = o;
        o.x = accv[0][0] * sv; o.y = accv[0][1] * sv;
        o.z = accv[0][2] * sv; o.w = accv[1][0] * sv;
        v4[2] = o;
        o.x = accv[1][1] * sv; o.y = accv[1][2] * sv;
        o.z = accv[2][0] * sv; o.w = accv[2][1] * sv;
        v4[3] = o;
        o.x = accv[2][2] * sv; o.y = accv[3][0] * sv;
        o.z = accv[3][1] * sv; o.w = accv[3][2] * sv;
        v4[4] = o;
        o.x = accv[4][0] * sv; o.y = accv[4][1] * sv;
        o.z = accv[4][2] * sv; o.w = accv[5][0] * sv;
        v4[5] = o;
        o.x = accv[5][1] * sv; o.y = accv[5][2] * sv;
        o.z = accv[6][0] * sv; o.w = accv[6][1] * sv;
        v4[6] = o;
        o.x = accv[6][2] * sv; o.y = accv[7][0] * sv;
        o.z = accv[7][1] * sv; o.w = accv[7][2] * sv;
        v4[7] = o;
      }
    }
  }
}

// ---------------- gather: one wave per node over its CSR segment ----------------
__global__ __launch_bounds__(256) void gather_kernel(
    const int* __restrict__ off,
    const float* __restrict__ exo,
    const float* __restrict__ wout,
    float* __restrict__ out)
{
  const int tid  = threadIdx.x;
  const int wave = tid >> 6;
  const int lane = tid & 63;
  const int n = blockIdx.x * 4 + wave;
  if (n >= NN) return;
  const int start = off[n];
  const int end   = off[n + 1];
  const int cnt   = end - start;

  float zp = 0.f;
  for (int j = start + lane; j < end; j += 64) zp += exo[j];
#pragma unroll
  for (int s = 32; s >= 1; s >>= 1) zp += __shfl_xor(zp, s, 64);

  const int l  = lane & 31;
  const int hh = lane >> 5;
  float acc = 0.f;
  for (int j = start + hh; j < end; j += 2)
    acc += wout[(size_t)j * 32 + l];
  acc += __shfl_xor(acc, 32, 64);

  if (lane < 32) {
    float s = (cnt > 0 && zp > 0.f) ? sqrtf((float)cnt / zp) : 0.f;
    out[(size_t)n * 32 + l] = acc * s;
  }
}

extern "C" void kernel_launch(void* const* d_in, const int* in_sizes, int n_in,
                              void* d_out, int out_size, void* d_ws, size_t ws_size,
                              hipStream_t stream)
{
  const float* node_attr  = (const float*)d_in[0];
  const int*   edge_index = (const int*)  d_in[1];
  const float* edge_attr  = (const float*)d_in[2];
  const float* edge_sh    = (const float*)d_in[3];
  const float* Wq0 = (const float*)d_in[4];
  const float* Wq1 = (const float*)d_in[5];
  const float* kW1 = (const float*)d_in[6];
  const float* kW2 = (const float*)d_in[7];
  const float* vW1 = (const float*)d_in[8];
  const float* vW2 = (const float*)d_in[9];
  const float* Wd0 = (const float*)d_in[10];
  const float* Wd1 = (const float*)d_in[11];
  float* out = (float*)d_out;

  float* ws = (float*)d_ws;
  float* qd     = ws;                    // 200000
  float* qvd    = qd   + 200000;         // 600000
  float* kW1T   = qvd  + 600000;         // 1024
  float* vW1T   = kW1T + 1024;           // 1024
  unsigned short* afrag = (unsigned short*)(vW1T + 1024);   // 40960 ushorts
  int* hist   = (int*)((char*)afrag + 81920);               // 25024
  int* off    = hist + 25024;                               // 25056 (NN+1)
  int* cursor = off  + 25056;                               // 25024
  float* exo  = (float*)(cursor + 25024);                   // 200000
  float* wout = exo + 200000;                               // 6400000

  hipMemsetAsync(hist, 0, 25024 * sizeof(int), stream);

  prep_kernel<<<160, 256, 0, stream>>>(
      kW1, kW2, vW1, vW2, node_attr, Wq0, Wq1, Wd0, Wd1, edge_index,
      kW1T, vW1T, afrag, qd, qvd, hist);
  scan_kernel<<<1, 1024, 0, stream>>>(hist, off, cursor);
  edge_kernel<<<(NE + 255) / 256, 256, 0, stream>>>(
      node_attr, edge_index, edge_attr, edge_sh,
      kW1T, vW1T, afrag, qd, qvd, cursor, exo, wout);
  gather_kernel<<<(NN + 3) / 4, 256, 0, stream>>>(off, exo, wout, out);
}

// Round 7
// 263.373 us; speedup vs baseline: 1.9593x; 1.4327x over previous
//
#include <hip/hip_runtime.h>
#include <math.h>

#define NE 200000
#define NN 25000

static constexpr float INV_SQRT3  = 0.5773502691896258f;
static constexpr float INV_SQRT2  = 0.7071067811865476f;
static constexpr float INV_SQRT8  = 0.3535533905932738f;
static constexpr float INV_SQRT24 = 0.2041241452319315f;

typedef __attribute__((ext_vector_type(8))) short bf16x8;
typedef __attribute__((ext_vector_type(4))) float f32x4;

union U16x8 { uint4 u; bf16x8 v; };

__device__ __forceinline__ unsigned f2bf1(float f) {
  unsigned u = __float_as_uint(f);
  return (u + 0x7FFFu + ((u >> 16) & 1u)) >> 16;
}
__device__ __forceinline__ unsigned packbf(float a, float b) {
  return f2bf1(a) | (f2bf1(b) << 16);
}
__device__ __forceinline__ float bflo(unsigned u) { return __uint_as_float(u << 16); }
__device__ __forceinline__ float bfhi(unsigned u) { return __uint_as_float(u & 0xFFFF0000u); }

// ---------------- fused prep: W1T transpose + W2 A-frags + node q's + dst histogram ----
__global__ __launch_bounds__(256) void prep_kernel(
    const float* __restrict__ kW1, const float* __restrict__ kW2,
    const float* __restrict__ vW1, const float* __restrict__ vW2,
    const float* __restrict__ node_attr,
    const float* __restrict__ Wq0, const float* __restrict__ Wq1,
    const float* __restrict__ Wd0, const float* __restrict__ Wd1,
    const int*   __restrict__ edge_index,
    float* __restrict__ kW1T, float* __restrict__ vW1T,
    unsigned short* __restrict__ afrag,
    float* __restrict__ qd, float* __restrict__ qvd,
    int* __restrict__ hist)
{
  int t = blockIdx.x * blockDim.x + threadIdx.x;   // 40960 threads
  if (t < 1024) {
    int j = t >> 6;
    int r = t & 63;
    kW1T[r * 16 + j] = kW1[t];
    vW1T[r * 16 + j] = vW1[t];
  }
  if (t < 40960) {
    int j    = t & 7;
    int lane = (t >> 3) & 63;
    int kk   = (t >> 9) & 1;
    int ot   = (t >> 10) & 1;
    int ci   = t >> 11;
    int b    = ci / 10;
    int rem  = ci - b * 10;
    int p    = rem >> 1;
    int hf   = rem & 1;
    int r    = kk * 32 + ((lane >> 4) << 3) + j;
    int o    = p * 64 + hf * 32 + ot * 16 + (lane & 15);
    const float* W = b ? vW2 : kW2;
    afrag[t] = (unsigned short)f2bf1(W[r * 320 + o]);
  }
#pragma unroll
  for (int i = 0; i < 5; ++i) {
    int e = t * 5 + i;
    if (e < NE) atomicAdd(&hist[edge_index[NE + e]], 1);
  }
  if (t < NN) {
    int n = t;
    float ns[8], nv[24];
#pragma unroll
    for (int i = 0; i < 8; ++i)  ns[i] = node_attr[n * 32 + i];
#pragma unroll
    for (int i = 0; i < 24; ++i) nv[i] = node_attr[n * 32 + 8 + i];
    float qs[8];
#pragma unroll
    for (int m = 0; m < 8; ++m) {
      float a = 0.f;
#pragma unroll
      for (int i = 0; i < 8; ++i) a = fmaf(ns[i], Wq0[i * 8 + m], a);
      qs[m] = a * INV_SQRT8;
    }
#pragma unroll
    for (int k = 0; k < 8; ++k) {
      float a = 0.f;
#pragma unroll
      for (int m = 0; m < 8; ++m) a = fmaf(qs[m], Wd0[m * 8 + k], a);
      qd[n * 8 + k] = a;
    }
    float qv[24];
#pragma unroll
    for (int k = 0; k < 8; ++k) {
#pragma unroll
      for (int c = 0; c < 3; ++c) {
        float a = 0.f;
#pragma unroll
        for (int m = 0; m < 8; ++m) a = fmaf(nv[m * 3 + c], Wq1[m * 8 + k], a);
        qv[k * 3 + c] = a * INV_SQRT8;
      }
    }
#pragma unroll
    for (int k = 0; k < 8; ++k) {
#pragma unroll
      for (int c = 0; c < 3; ++c) {
        float a = 0.f;
#pragma unroll
        for (int m = 0; m < 8; ++m) a = fmaf(qv[m * 3 + c], Wd1[m * 8 + k], a);
        qvd[n * 24 + k * 3 + c] = a;
      }
    }
  }
}

// ---------------- chunked shfl scan: hist -> off (NN+1), cursor ----------------
__global__ __launch_bounds__(1024) void scan_kernel(
    const int* __restrict__ hist, int* __restrict__ off, int* __restrict__ cursor)
{
  __shared__ int wsum[16];
  const int tid  = threadIdx.x;
  const int lane = tid & 63;
  const int wv   = tid >> 6;
  const int base = tid * 25;
  int loc[25];
  int s = 0;
#pragma unroll
  for (int i = 0; i < 25; ++i) {
    int idx = base + i;
    int v = (idx < NN) ? hist[idx] : 0;
    loc[i] = s;
    s += v;
  }
  int incl = s;
#pragma unroll
  for (int d = 1; d < 64; d <<= 1) {
    int t = __shfl_up(incl, d, 64);
    if (lane >= d) incl += t;
  }
  int wexcl = incl - s;
  if (lane == 63) wsum[wv] = incl;
  __syncthreads();
  if (wv == 0 && lane < 16) {
    int v = wsum[lane];
    int inc2 = v;
#pragma unroll
    for (int d = 1; d < 16; d <<= 1) {
      int t = __shfl_up(inc2, d, 64);
      if (lane >= d) inc2 += t;
    }
    wsum[lane] = inc2 - v;
  }
  __syncthreads();
  int tbase = wsum[wv] + wexcl;
#pragma unroll
  for (int i = 0; i < 25; ++i) {
    int idx = base + i;
    if (idx < NN) { int e = tbase + loc[i]; off[idx] = e; cursor[idx] = e; }
  }
  if (tid == 1023) off[NN] = tbase + s;
}

// ---------------- main edge pass (MFMA, CSR output) ----------------
// Spill control (R5/R6 spilled at the 256-VGPR cap because the 10-chunk
// loop was fully unrolled -> load hoisting blew up live ranges):
//  - chunk loop is #pragma unroll 1 (p becomes runtime; contraction branches
//    are wave-uniform -> cheap)
//  - w-chunk consumed in two 16-value halves, never a wv[32]
//  - h computed in groups of 8 and packed straight to LDS
__global__ __launch_bounds__(256) void edge_kernel(
    const float* __restrict__ node_attr,
    const int*   __restrict__ edge_index,
    const float* __restrict__ edge_attr,
    const float* __restrict__ edge_sh,
    const float* __restrict__ kW1T, const float* __restrict__ vW1T,
    const unsigned short* __restrict__ afrag,
    const float* __restrict__ qd,   const float* __restrict__ qvd,
    int* __restrict__ cursor,
    float* __restrict__ exo, float* __restrict__ wout)
{
  __shared__ unsigned char smem[65536];
  float* sW1 = (float*)smem;                              // 8 KiB
  const int tid  = threadIdx.x;
  const int lane = tid & 63;
  const int wave = tid >> 6;
  const int l15  = lane & 15;
  const int quad = lane >> 4;
  unsigned char* sh  = smem + 8192  + wave * 9216;        // 64 x 144 B
  unsigned char* swp = smem + 45056 + wave * 5120;        // 64 x 80 B

  ((float4*)sW1)[tid]       = ((const float4*)kW1T)[tid];
  ((float4*)sW1)[256 + tid] = ((const float4*)vW1T)[tid];
  __syncthreads();

  const int e = blockIdx.x * 256 + tid;
  const bool valid = (e < NE);
  const int el  = valid ? e : (NE - 1);
  const int src = edge_index[el];
  const int dst = edge_index[NE + el];

  int pos = 0;
  if (valid) pos = atomicAdd(&cursor[dst], 1);

  const float s0  = edge_sh[el * 4 + 0];
  const float s1x = edge_sh[el * 4 + 1];
  const float s1y = edge_sh[el * 4 + 2];
  const float s1z = edge_sh[el * 4 + 3];

  float xs[8], xv[8][3];
  {
    const float4* na4 = (const float4*)(node_attr + (size_t)src * 32);
    float tmp[32];
#pragma unroll
    for (int i = 0; i < 8; ++i) {
      float4 v = na4[i];
      tmp[4*i+0] = v.x; tmp[4*i+1] = v.y; tmp[4*i+2] = v.z; tmp[4*i+3] = v.w;
    }
#pragma unroll
    for (int m = 0; m < 8; ++m) xs[m] = tmp[m];
#pragma unroll
    for (int m = 0; m < 8; ++m) {
      xv[m][0] = tmp[8 + 3*m + 0];
      xv[m][1] = tmp[8 + 3*m + 1];
      xv[m][2] = tmp[8 + 3*m + 2];
    }
  }

  const uint4* AF = (const uint4*)afrag;
  float ex = 0.f;

#pragma unroll 1
  for (int b = 0; b < 2; ++b) {
    // ---- h = silu(ea @ W1 / 4), 8 rows at a time, packed straight to LDS ----
    {
      float ea[16];
      const float4* ea4 = (const float4*)(edge_attr + (size_t)el * 16);
#pragma unroll
      for (int i = 0; i < 4; ++i) {
        float4 v = ea4[i];
        ea[4*i+0] = v.x; ea[4*i+1] = v.y; ea[4*i+2] = v.z; ea[4*i+3] = v.w;
      }
      const float* W1base = sW1 + b * 1024;
      unsigned char* myrow = sh + lane * 144;
#pragma unroll 1
      for (int g = 0; g < 8; ++g) {
        float hg[8];
#pragma unroll
        for (int rr = 0; rr < 8; ++rr) {
          const float4* rp = (const float4*)(W1base + (g * 8 + rr) * 16);
          float4 x0 = rp[0], x1 = rp[1], x2 = rp[2], x3 = rp[3];
          float a0 = 0.f, a1 = 0.f;
          a0 = fmaf(ea[ 0], x0.x, a0); a0 = fmaf(ea[ 1], x0.y, a0);
          a0 = fmaf(ea[ 2], x0.z, a0); a0 = fmaf(ea[ 3], x0.w, a0);
          a1 = fmaf(ea[ 4], x1.x, a1); a1 = fmaf(ea[ 5], x1.y, a1);
          a1 = fmaf(ea[ 6], x1.z, a1); a1 = fmaf(ea[ 7], x1.w, a1);
          a0 = fmaf(ea[ 8], x2.x, a0); a0 = fmaf(ea[ 9], x2.y, a0);
          a0 = fmaf(ea[10], x2.z, a0); a0 = fmaf(ea[11], x2.w, a0);
          a1 = fmaf(ea[12], x3.x, a1); a1 = fmaf(ea[13], x3.y, a1);
          a1 = fmaf(ea[14], x3.z, a1); a1 = fmaf(ea[15], x3.w, a1);
          float a = (a0 + a1) * 0.25f;
          hg[rr] = a / (1.f + __expf(-a));
        }
        uint4 pk;
        pk.x = packbf(hg[0], hg[1]);
        pk.y = packbf(hg[2], hg[3]);
        pk.z = packbf(hg[4], hg[5]);
        pk.w = packbf(hg[6], hg[7]);
        *(uint4*)(myrow + g * 16) = pk;
      }
    }

    // ---- B-fragments (H), read once, reused for all 10 chunks ----
    bf16x8 B[4][2];
#pragma unroll
    for (int et = 0; et < 4; ++et) {
#pragma unroll
      for (int kk = 0; kk < 2; ++kk) {
        U16x8 cv;
        cv.u = *(const uint4*)(sh + (et*16 + l15) * 144 + kk * 64 + quad * 16);
        B[et][kk] = cv.v;
      }
    }

    float accs[8];
    float accv[8][3];
#pragma unroll
    for (int n = 0; n < 8; ++n) {
      accs[n] = 0.f;
      accv[n][0] = 0.f; accv[n][1] = 0.f; accv[n][2] = 0.f;
    }

    // ---- 10 chunks, NOT unrolled (spill control) ----
#pragma unroll 1
    for (int cc = 0; cc < 10; ++cc) {
      const int p  = cc >> 1;
      const int hf = cc & 1;
      const int ci = b * 10 + cc;
      U16x8 a00, a01, a10, a11;
      a00.u = AF[(ci*4 + 0) * 64 + lane];
      a01.u = AF[(ci*4 + 1) * 64 + lane];
      a10.u = AF[(ci*4 + 2) * 64 + lane];
      a11.u = AF[(ci*4 + 3) * 64 + lane];

#pragma unroll
      for (int et = 0; et < 4; ++et) {
        f32x4 c0 = {0.f, 0.f, 0.f, 0.f};
        f32x4 c1 = {0.f, 0.f, 0.f, 0.f};
        c0 = __builtin_amdgcn_mfma_f32_16x16x32_bf16(a00.v, B[et][0], c0, 0, 0, 0);
        c0 = __builtin_amdgcn_mfma_f32_16x16x32_bf16(a01.v, B[et][1], c0, 0, 0, 0);
        c1 = __builtin_amdgcn_mfma_f32_16x16x32_bf16(a10.v, B[et][0], c1, 0, 0, 0);
        c1 = __builtin_amdgcn_mfma_f32_16x16x32_bf16(a11.v, B[et][1], c1, 0, 0, 0);
        unsigned char* wrow = swp + (et*16 + l15) * 80;
        uint2 p0; p0.x = packbf(c0.x, c0.y); p0.y = packbf(c0.z, c0.w);
        uint2 p1; p1.x = packbf(c1.x, c1.y); p1.y = packbf(c1.z, c1.w);
        *(uint2*)(wrow + quad * 8)      = p0;
        *(uint2*)(wrow + 32 + quad * 8) = p1;
      }

      // consume w-chunk in two 16-value halves (never a full wv[32])
      const uint4* wr = (const uint4*)(swp + (size_t)lane * 80);
#pragma unroll
      for (int h2 = 0; h2 < 2; ++h2) {
        uint4 qa = wr[h2 * 2], qb = wr[h2 * 2 + 1];
        float wvv[16];
        {
          unsigned qs_[8] = {qa.x,qa.y,qa.z,qa.w, qb.x,qb.y,qb.z,qb.w};
#pragma unroll
          for (int i = 0; i < 8; ++i) {
            wvv[2*i]   = bflo(qs_[i]);
            wvv[2*i+1] = bfhi(qs_[i]);
          }
        }
#pragma unroll
        for (int mm = 0; mm < 2; ++mm) {
          const int m = hf * 4 + h2 * 2 + mm;
          const float* wm = &wvv[mm * 8];
          if (p == 0) {
            float g = xs[m] * s0;
#pragma unroll
            for (int n = 0; n < 8; ++n) accs[n] = fmaf(wm[n], g, accs[n]);
          } else if (p == 1) {
            float a = xs[m];
            float gx = a * s1x, gy = a * s1y, gz = a * s1z;
#pragma unroll
            for (int n = 0; n < 8; ++n) {
              accv[n][0] = fmaf(wm[n], gx, accv[n][0]);
              accv[n][1] = fmaf(wm[n], gy, accv[n][1]);
              accv[n][2] = fmaf(wm[n], gz, accv[n][2]);
            }
          } else if (p == 2) {
            float gx = xv[m][0] * s0, gy = xv[m][1] * s0, gz = xv[m][2] * s0;
#pragma unroll
            for (int n = 0; n < 8; ++n) {
              accv[n][0] = fmaf(wm[n], gx, accv[n][0]);
              accv[n][1] = fmaf(wm[n], gy, accv[n][1]);
              accv[n][2] = fmaf(wm[n], gz, accv[n][2]);
            }
          } else if (p == 3) {
            float dm = (xv[m][0]*s1x + xv[m][1]*s1y + xv[m][2]*s1z) * INV_SQRT3;
#pragma unroll
            for (int n = 0; n < 8; ++n) accs[n] = fmaf(wm[n], dm, accs[n]);
          } else {
            float crx = (xv[m][1]*s1z - xv[m][2]*s1y) * INV_SQRT2;
            float cry = (xv[m][2]*s1x - xv[m][0]*s1z) * INV_SQRT2;
            float crz = (xv[m][0]*s1y - xv[m][1]*s1x) * INV_SQRT2;
#pragma unroll
            for (int n = 0; n < 8; ++n) {
              accv[n][0] = fmaf(wm[n], crx, accv[n][0]);
              accv[n][1] = fmaf(wm[n], cry, accv[n][1]);
              accv[n][2] = fmaf(wm[n], crz, accv[n][2]);
            }
          }
        }
      }
    }

    if (b == 0) {
      float lg = 0.f, lv = 0.f;
#pragma unroll
      for (int n = 0; n < 8; ++n) lg = fmaf(accs[n], qd[dst * 8 + n], lg);
#pragma unroll
      for (int n = 0; n < 8; ++n) {
#pragma unroll
        for (int c = 0; c < 3; ++c)
          lv = fmaf(accv[n][c], qvd[dst * 24 + n * 3 + c], lv);
      }
      float logit = (lg * (1.f / 32.f) +
                     lv * (0.125f * INV_SQRT24) * INV_SQRT3) * 0.25f;
      ex = __expf(logit);
      if (valid) exo[pos] = ex;
    } else {
      if (valid) {
        float a = sqrtf(ex);
        const float ss = a * (1.f / 32.f);
        const float sv = a * (0.125f * INV_SQRT24);
        float4* v4 = (float4*)(wout + (size_t)pos * 32);
        float4 o;
        o.x = accs[0] * ss; o.y = accs[1] * ss;
        o.z = accs[2] * ss; o.w = accs[3] * ss;
        v4[0] = o;
        o.x = accs[4] * ss; o.y = accs[5] * ss;
        o.z = accs[6] * ss; o.w = accs[7] * ss;
        v4[1] = o;
        o.x = accv[0][0] * sv; o.y = accv[0][1] * sv;
        o.z = accv[0][2] * sv; o.w = accv[1][0] * sv;
        v4[2] = o;
        o.x = accv[1][1] * sv; o.y = accv[1][2] * sv;
        o.z = accv[2][0] * sv; o.w = accv[2][1] * sv;
        v4[3] = o;
        o.x = accv[2][2] * sv; o.y = accv[3][0] * sv;
        o.z = accv[3][1] * sv; o.w = accv[3][2] * sv;
        v4[4] = o;
        o.x = accv[4][0] * sv; o.y = accv[4][1] * sv;
        o.z = accv[4][2] * sv; o.w = accv[5][0] * sv;
        v4[5] = o;
        o.x = accv[5][1] * sv; o.y = accv[5][2] * sv;
        o.z = accv[6][0] * sv; o.w = accv[6][1] * sv;
        v4[6] = o;
        o.x = accv[6][2] * sv; o.y = accv[7][0] * sv;
        o.z = accv[7][1] * sv; o.w = accv[7][2] * sv;
        v4[7] = o;
      }
    }
  }
}

// ---------------- gather: one wave per node over its CSR segment ----------------
__global__ __launch_bounds__(256) void gather_kernel(
    const int* __restrict__ off,
    const float* __restrict__ exo,
    const float* __restrict__ wout,
    float* __restrict__ out)
{
  const int tid  = threadIdx.x;
  const int wave = tid >> 6;
  const int lane = tid & 63;
  const int n = blockIdx.x * 4 + wave;
  if (n >= NN) return;
  const int start = off[n];
  const int end   = off[n + 1];
  const int cnt   = end - start;

  float zp = 0.f;
  for (int j = start + lane; j < end; j += 64) zp += exo[j];
#pragma unroll
  for (int s = 32; s >= 1; s >>= 1) zp += __shfl_xor(zp, s, 64);

  const int l  = lane & 31;
  const int hh = lane >> 5;
  float acc = 0.f;
  for (int j = start + hh; j < end; j += 2)
    acc += wout[(size_t)j * 32 + l];
  acc += __shfl_xor(acc, 32, 64);

  if (lane < 32) {
    float s = (cnt > 0 && zp > 0.f) ? sqrtf((float)cnt / zp) : 0.f;
    out[(size_t)n * 32 + l] = acc * s;
  }
}

extern "C" void kernel_launch(void* const* d_in, const int* in_sizes, int n_in,
                              void* d_out, int out_size, void* d_ws, size_t ws_size,
                              hipStream_t stream)
{
  const float* node_attr  = (const float*)d_in[0];
  const int*   edge_index = (const int*)  d_in[1];
  const float* edge_attr  = (const float*)d_in[2];
  const float* edge_sh    = (const float*)d_in[3];
  const float* Wq0 = (const float*)d_in[4];
  const float* Wq1 = (const float*)d_in[5];
  const float* kW1 = (const float*)d_in[6];
  const float* kW2 = (const float*)d_in[7];
  const float* vW1 = (const float*)d_in[8];
  const float* vW2 = (const float*)d_in[9];
  const float* Wd0 = (const float*)d_in[10];
  const float* Wd1 = (const float*)d_in[11];
  float* out = (float*)d_out;

  float* ws = (float*)d_ws;
  float* qd     = ws;                    // 200000
  float* qvd    = qd   + 200000;         // 600000
  float* kW1T   = qvd  + 600000;         // 1024
  float* vW1T   = kW1T + 1024;           // 1024
  unsigned short* afrag = (unsigned short*)(vW1T + 1024);   // 40960 ushorts
  int* hist   = (int*)((char*)afrag + 81920);               // 25024
  int* off    = hist + 25024;                               // 25056 (NN+1)
  int* cursor = off  + 25056;                               // 25024
  float* exo  = (float*)(cursor + 25024);                   // 200000
  float* wout = exo + 200000;                               // 6400000

  hipMemsetAsync(hist, 0, 25024 * sizeof(int), stream);

  prep_kernel<<<160, 256, 0, stream>>>(
      kW1, kW2, vW1, vW2, node_attr, Wq0, Wq1, Wd0, Wd1, edge_index,
      kW1T, vW1T, afrag, qd, qvd, hist);
  scan_kernel<<<1, 1024, 0, stream>>>(hist, off, cursor);
  edge_kernel<<<(NE + 255) / 256, 256, 0, stream>>>(
      node_attr, edge_index, edge_attr, edge_sh,
      kW1T, vW1T, afrag, qd, qvd, cursor, exo, wout);
  gather_kernel<<<(NN + 3) / 4, 256, 0, stream>>>(off, exo, wout, out);
}

// Round 8
// 247.684 us; speedup vs baseline: 2.0834x; 1.0633x over previous
//
#include <hip/hip_runtime.h>
#include <math.h>

#define NE 200000
#define NN 25000

static constexpr float INV_SQRT3  = 0.5773502691896258f;
static constexpr float INV_SQRT2  = 0.7071067811865476f;
static constexpr float INV_SQRT8  = 0.3535533905932738f;
static constexpr float INV_SQRT24 = 0.2041241452319315f;

typedef __attribute__((ext_vector_type(8))) short bf16x8;
typedef __attribute__((ext_vector_type(4))) float f32x4;

union U16x8 { uint4 u; bf16x8 v; };

__device__ __forceinline__ unsigned f2bf1(float f) {
  unsigned u = __float_as_uint(f);
  return (u + 0x7FFFu + ((u >> 16) & 1u)) >> 16;
}
__device__ __forceinline__ unsigned packbf(float a, float b) {
  return f2bf1(a) | (f2bf1(b) << 16);
}
__device__ __forceinline__ float bflo(unsigned u) { return __uint_as_float(u << 16); }
__device__ __forceinline__ float bfhi(unsigned u) { return __uint_as_float(u & 0xFFFF0000u); }

// ---------------- fused prep: W2 A-frags + W1 A-frags + node q's + dst histogram ----
__global__ __launch_bounds__(256) void prep_kernel(
    const float* __restrict__ kW1, const float* __restrict__ kW2,
    const float* __restrict__ vW1, const float* __restrict__ vW2,
    const float* __restrict__ node_attr,
    const float* __restrict__ Wq0, const float* __restrict__ Wq1,
    const float* __restrict__ Wd0, const float* __restrict__ Wd1,
    const int*   __restrict__ edge_index,
    unsigned short* __restrict__ afrag,
    unsigned short* __restrict__ afrag1,
    float* __restrict__ qd, float* __restrict__ qvd,
    int* __restrict__ hist)
{
  int t = blockIdx.x * blockDim.x + threadIdx.x;   // 40960 threads
  // layer-1 A-frags: mfma 16x16x32, A[m=r][k] = W1[k&15][r], W1 is (16,64)
  if (t < 4096) {
    int j    = t & 7;
    int lane = (t >> 3) & 63;
    int rt   = (t >> 9) & 3;
    int b    = (t >> 11) & 1;
    int quad = lane >> 4;
    int k    = quad * 8 + j;
    int jeff = k & 15;
    int r    = rt * 16 + (lane & 15);
    const float* W = b ? vW1 : kW1;
    afrag1[t] = (unsigned short)f2bf1(W[jeff * 64 + r]);
  }
  // layer-2 A-frags (unchanged from R7)
  if (t < 40960) {
    int j    = t & 7;
    int lane = (t >> 3) & 63;
    int kk   = (t >> 9) & 1;
    int ot   = (t >> 10) & 1;
    int ci   = t >> 11;
    int b    = ci / 10;
    int rem  = ci - b * 10;
    int p    = rem >> 1;
    int hf   = rem & 1;
    int r    = kk * 32 + ((lane >> 4) << 3) + j;
    int o    = p * 64 + hf * 32 + ot * 16 + (lane & 15);
    const float* W = b ? vW2 : kW2;
    afrag[t] = (unsigned short)f2bf1(W[r * 320 + o]);
  }
#pragma unroll
  for (int i = 0; i < 5; ++i) {
    int e = t * 5 + i;
    if (e < NE) atomicAdd(&hist[edge_index[NE + e]], 1);
  }
  if (t < NN) {
    int n = t;
    float ns[8], nv[24];
#pragma unroll
    for (int i = 0; i < 8; ++i)  ns[i] = node_attr[n * 32 + i];
#pragma unroll
    for (int i = 0; i < 24; ++i) nv[i] = node_attr[n * 32 + 8 + i];
    float qs[8];
#pragma unroll
    for (int m = 0; m < 8; ++m) {
      float a = 0.f;
#pragma unroll
      for (int i = 0; i < 8; ++i) a = fmaf(ns[i], Wq0[i * 8 + m], a);
      qs[m] = a * INV_SQRT8;
    }
#pragma unroll
    for (int k = 0; k < 8; ++k) {
      float a = 0.f;
#pragma unroll
      for (int m = 0; m < 8; ++m) a = fmaf(qs[m], Wd0[m * 8 + k], a);
      qd[n * 8 + k] = a;
    }
    float qv[24];
#pragma unroll
    for (int k = 0; k < 8; ++k) {
#pragma unroll
      for (int c = 0; c < 3; ++c) {
        float a = 0.f;
#pragma unroll
        for (int m = 0; m < 8; ++m) a = fmaf(nv[m * 3 + c], Wq1[m * 8 + k], a);
        qv[k * 3 + c] = a * INV_SQRT8;
      }
    }
#pragma unroll
    for (int k = 0; k < 8; ++k) {
#pragma unroll
      for (int c = 0; c < 3; ++c) {
        float a = 0.f;
#pragma unroll
        for (int m = 0; m < 8; ++m) a = fmaf(qv[m * 3 + c], Wd1[m * 8 + k], a);
        qvd[n * 24 + k * 3 + c] = a;
      }
    }
  }
}

// ---------------- chunked shfl scan: hist -> off (NN+1), cursor ----------------
__global__ __launch_bounds__(1024) void scan_kernel(
    const int* __restrict__ hist, int* __restrict__ off, int* __restrict__ cursor)
{
  __shared__ int wsum[16];
  const int tid  = threadIdx.x;
  const int lane = tid & 63;
  const int wv   = tid >> 6;
  const int base = tid * 25;
  int loc[25];
  int s = 0;
#pragma unroll
  for (int i = 0; i < 25; ++i) {
    int idx = base + i;
    int v = (idx < NN) ? hist[idx] : 0;
    loc[i] = s;
    s += v;
  }
  int incl = s;
#pragma unroll
  for (int d = 1; d < 64; d <<= 1) {
    int t = __shfl_up(incl, d, 64);
    if (lane >= d) incl += t;
  }
  int wexcl = incl - s;
  if (lane == 63) wsum[wv] = incl;
  __syncthreads();
  if (wv == 0 && lane < 16) {
    int v = wsum[lane];
    int inc2 = v;
#pragma unroll
    for (int d = 1; d < 16; d <<= 1) {
      int t = __shfl_up(inc2, d, 64);
      if (lane >= d) inc2 += t;
    }
    wsum[lane] = inc2 - v;
  }
  __syncthreads();
  int tbase = wsum[wv] + wexcl;
#pragma unroll
  for (int i = 0; i < 25; ++i) {
    int idx = base + i;
    if (idx < NN) { int e = tbase + loc[i]; off[idx] = e; cursor[idx] = e; }
  }
  if (tid == 1023) off[NN] = tbase + s;
}

// ---------------- main edge pass (all-MFMA, CSR output) ----------------
// Layer-1 h-GEMM is MFMA: ea packed bf16 hi+lo into k halves of 16x16x32
// (error-compensated split), W1 A-frags prefragmented (afrag1). No W1 in
// LDS, no __syncthreads. One 9216B per-wave LDS region serves sequentially
// as: ea frags (5120B) -> h rows (9216B) -> w-chunk buffer (5120B).
// 36 KiB LDS/block -> 3-4 blocks/CU (R7's 64 KiB capped at 2).
__global__ __launch_bounds__(256) void edge_kernel(
    const float* __restrict__ node_attr,
    const int*   __restrict__ edge_index,
    const float* __restrict__ edge_attr,
    const float* __restrict__ edge_sh,
    const unsigned short* __restrict__ afrag1,
    const unsigned short* __restrict__ afrag,
    const float* __restrict__ qd,   const float* __restrict__ qvd,
    int* __restrict__ cursor,
    float* __restrict__ exo, float* __restrict__ wout)
{
  __shared__ unsigned char smem[36864];
  const int tid  = threadIdx.x;
  const int lane = tid & 63;
  const int wave = tid >> 6;
  const int l15  = lane & 15;
  const int quad = lane >> 4;
  unsigned char* reg9k = smem + wave * 9216;   // per-wave region
  unsigned char* sea = reg9k;                  // 64 x 80 B (ea hi/lo frags)
  unsigned char* sh  = reg9k;                  // 64 x 144 B (h rows)
  unsigned char* swp = reg9k;                  // 64 x 80 B (w chunks)

  const int e = blockIdx.x * 256 + tid;
  const bool valid = (e < NE);
  const int el  = valid ? e : (NE - 1);
  const int src = edge_index[el];
  const int dst = edge_index[NE + el];

  int pos = 0;
  if (valid) pos = atomicAdd(&cursor[dst], 1);

  const float s0  = edge_sh[el * 4 + 0];
  const float s1x = edge_sh[el * 4 + 1];
  const float s1y = edge_sh[el * 4 + 2];
  const float s1z = edge_sh[el * 4 + 3];

  // ---- stage ea as bf16 hi + lo (error-compensated) into sea ----
  {
    float ea[16];
    const float4* ea4 = (const float4*)(edge_attr + (size_t)el * 16);
#pragma unroll
    for (int i = 0; i < 4; ++i) {
      float4 v = ea4[i];
      ea[4*i+0] = v.x; ea[4*i+1] = v.y; ea[4*i+2] = v.z; ea[4*i+3] = v.w;
    }
    unsigned char* myrow = sea + lane * 80;
    unsigned hi[8];
    float lo[16];
#pragma unroll
    for (int i = 0; i < 8; ++i) {
      unsigned h0 = f2bf1(ea[2*i]);
      unsigned h1 = f2bf1(ea[2*i+1]);
      hi[i] = h0 | (h1 << 16);
      lo[2*i]   = ea[2*i]   - bflo(h0);
      lo[2*i+1] = ea[2*i+1] - bflo(h1);
    }
    uint4 w0 = {hi[0], hi[1], hi[2], hi[3]};
    uint4 w1 = {hi[4], hi[5], hi[6], hi[7]};
    *(uint4*)(myrow)      = w0;
    *(uint4*)(myrow + 16) = w1;
    uint4 w2, w3;
    w2.x = packbf(lo[0], lo[1]);   w2.y = packbf(lo[2], lo[3]);
    w2.z = packbf(lo[4], lo[5]);   w2.w = packbf(lo[6], lo[7]);
    w3.x = packbf(lo[8], lo[9]);   w3.y = packbf(lo[10], lo[11]);
    w3.z = packbf(lo[12], lo[13]); w3.w = packbf(lo[14], lo[15]);
    *(uint4*)(myrow + 32) = w2;
    *(uint4*)(myrow + 48) = w3;
  }

  // ---- B1 fragments (ea), branch-independent, read once ----
  // B[k=quad*8+j][n=et*16+l15]: quads 0-1 read hi (k<16), 2-3 read lo.
  U16x8 B1[4];
#pragma unroll
  for (int et = 0; et < 4; ++et)
    B1[et].u = *(const uint4*)(sea + (et*16 + l15) * 80 + quad * 16);

  // ---- own-edge node values ----
  float xs[8], xv[8][3];
  {
    const float4* na4 = (const float4*)(node_attr + (size_t)src * 32);
    float tmp[32];
#pragma unroll
    for (int i = 0; i < 8; ++i) {
      float4 v = na4[i];
      tmp[4*i+0] = v.x; tmp[4*i+1] = v.y; tmp[4*i+2] = v.z; tmp[4*i+3] = v.w;
    }
#pragma unroll
    for (int m = 0; m < 8; ++m) xs[m] = tmp[m];
#pragma unroll
    for (int m = 0; m < 8; ++m) {
      xv[m][0] = tmp[8 + 3*m + 0];
      xv[m][1] = tmp[8 + 3*m + 1];
      xv[m][2] = tmp[8 + 3*m + 2];
    }
  }

  const uint4* AF  = (const uint4*)afrag;
  const uint4* AF1 = (const uint4*)afrag1;
  float ex = 0.f;

#pragma unroll 1
  for (int b = 0; b < 2; ++b) {
    // ---- layer-1: h = silu(ea @ W1 / 4) via 16 MFMA, write bf16 h to sh ----
#pragma unroll 1
    for (int rt = 0; rt < 4; ++rt) {
      U16x8 a1;
      a1.u = AF1[(b * 4 + rt) * 64 + lane];
#pragma unroll
      for (int et = 0; et < 4; ++et) {
        f32x4 c = {0.f, 0.f, 0.f, 0.f};
        c = __builtin_amdgcn_mfma_f32_16x16x32_bf16(a1.v, B1[et].v, c, 0, 0, 0);
        float hh[4];
#pragma unroll
        for (int i = 0; i < 4; ++i) {
          float x = c[i] * 0.25f;
          hh[i] = x / (1.f + __expf(-x));
        }
        uint2 pk;
        pk.x = packbf(hh[0], hh[1]);
        pk.y = packbf(hh[2], hh[3]);
        *(uint2*)(sh + (et*16 + l15) * 144 + (rt*16 + quad*4) * 2) = pk;
      }
    }

    // ---- B2 fragments (H) ----
    bf16x8 B[4][2];
#pragma unroll
    for (int et = 0; et < 4; ++et) {
#pragma unroll
      for (int kk = 0; kk < 2; ++kk) {
        U16x8 cv;
        cv.u = *(const uint4*)(sh + (et*16 + l15) * 144 + kk * 64 + quad * 16);
        B[et][kk] = cv.v;
      }
    }

    float accs[8];
    float accv[8][3];
#pragma unroll
    for (int n = 0; n < 8; ++n) {
      accs[n] = 0.f;
      accv[n][0] = 0.f; accv[n][1] = 0.f; accv[n][2] = 0.f;
    }

    // ---- 10 chunks, NOT unrolled (spill control) ----
#pragma unroll 1
    for (int cc = 0; cc < 10; ++cc) {
      const int p  = cc >> 1;
      const int hf = cc & 1;
      const int ci = b * 10 + cc;
      U16x8 a00, a01, a10, a11;
      a00.u = AF[(ci*4 + 0) * 64 + lane];
      a01.u = AF[(ci*4 + 1) * 64 + lane];
      a10.u = AF[(ci*4 + 2) * 64 + lane];
      a11.u = AF[(ci*4 + 3) * 64 + lane];

#pragma unroll
      for (int et = 0; et < 4; ++et) {
        f32x4 c0 = {0.f, 0.f, 0.f, 0.f};
        f32x4 c1 = {0.f, 0.f, 0.f, 0.f};
        c0 = __builtin_amdgcn_mfma_f32_16x16x32_bf16(a00.v, B[et][0], c0, 0, 0, 0);
        c0 = __builtin_amdgcn_mfma_f32_16x16x32_bf16(a01.v, B[et][1], c0, 0, 0, 0);
        c1 = __builtin_amdgcn_mfma_f32_16x16x32_bf16(a10.v, B[et][0], c1, 0, 0, 0);
        c1 = __builtin_amdgcn_mfma_f32_16x16x32_bf16(a11.v, B[et][1], c1, 0, 0, 0);
        unsigned char* wrow = swp + (et*16 + l15) * 80;
        uint2 p0; p0.x = packbf(c0.x, c0.y); p0.y = packbf(c0.z, c0.w);
        uint2 p1; p1.x = packbf(c1.x, c1.y); p1.y = packbf(c1.z, c1.w);
        *(uint2*)(wrow + quad * 8)      = p0;
        *(uint2*)(wrow + 32 + quad * 8) = p1;
      }

      // consume w-chunk in two 16-value halves
      const uint4* wr = (const uint4*)(swp + (size_t)lane * 80);
#pragma unroll
      for (int h2 = 0; h2 < 2; ++h2) {
        uint4 qa = wr[h2 * 2], qb = wr[h2 * 2 + 1];
        float wvv[16];
        {
          unsigned qs_[8] = {qa.x,qa.y,qa.z,qa.w, qb.x,qb.y,qb.z,qb.w};
#pragma unroll
          for (int i = 0; i < 8; ++i) {
            wvv[2*i]   = bflo(qs_[i]);
            wvv[2*i+1] = bfhi(qs_[i]);
          }
        }
#pragma unroll
        for (int mm = 0; mm < 2; ++mm) {
          const int m = hf * 4 + h2 * 2 + mm;
          const float* wm = &wvv[mm * 8];
          if (p == 0) {
            float g = xs[m] * s0;
#pragma unroll
            for (int n = 0; n < 8; ++n) accs[n] = fmaf(wm[n], g, accs[n]);
          } else if (p == 1) {
            float a = xs[m];
            float gx = a * s1x, gy = a * s1y, gz = a * s1z;
#pragma unroll
            for (int n = 0; n < 8; ++n) {
              accv[n][0] = fmaf(wm[n], gx, accv[n][0]);
              accv[n][1] = fmaf(wm[n], gy, accv[n][1]);
              accv[n][2] = fmaf(wm[n], gz, accv[n][2]);
            }
          } else if (p == 2) {
            float gx = xv[m][0] * s0, gy = xv[m][1] * s0, gz = xv[m][2] * s0;
#pragma unroll
            for (int n = 0; n < 8; ++n) {
              accv[n][0] = fmaf(wm[n], gx, accv[n][0]);
              accv[n][1] = fmaf(wm[n], gy, accv[n][1]);
              accv[n][2] = fmaf(wm[n], gz, accv[n][2]);
            }
          } else if (p == 3) {
            float dm = (xv[m][0]*s1x + xv[m][1]*s1y + xv[m][2]*s1z) * INV_SQRT3;
#pragma unroll
            for (int n = 0; n < 8; ++n) accs[n] = fmaf(wm[n], dm, accs[n]);
          } else {
            float crx = (xv[m][1]*s1z - xv[m][2]*s1y) * INV_SQRT2;
            float cry = (xv[m][2]*s1x - xv[m][0]*s1z) * INV_SQRT2;
            float crz = (xv[m][0]*s1y - xv[m][1]*s1x) * INV_SQRT2;
#pragma unroll
            for (int n = 0; n < 8; ++n) {
              accv[n][0] = fmaf(wm[n], crx, accv[n][0]);
              accv[n][1] = fmaf(wm[n], cry, accv[n][1]);
              accv[n][2] = fmaf(wm[n], crz, accv[n][2]);
            }
          }
        }
      }
    }

    if (b == 0) {
      float lg = 0.f, lv = 0.f;
#pragma unroll
      for (int n = 0; n < 8; ++n) lg = fmaf(accs[n], qd[dst * 8 + n], lg);
#pragma unroll
      for (int n = 0; n < 8; ++n) {
#pragma unroll
        for (int c = 0; c < 3; ++c)
          lv = fmaf(accv[n][c], qvd[dst * 24 + n * 3 + c], lv);
      }
      float logit = (lg * (1.f / 32.f) +
                     lv * (0.125f * INV_SQRT24) * INV_SQRT3) * 0.25f;
      ex = __expf(logit);
      if (valid) exo[pos] = ex;
    } else {
      if (valid) {
        float a = sqrtf(ex);
        const float ss = a * (1.f / 32.f);
        const float sv = a * (0.125f * INV_SQRT24);
        float4* v4 = (float4*)(wout + (size_t)pos * 32);
        float4 o;
        o.x = accs[0] * ss; o.y = accs[1] * ss;
        o.z = accs[2] * ss; o.w = accs[3] * ss;
        v4[0] = o;
        o.x = accs[4] * ss; o.y = accs[5] * ss;
        o.z = accs[6] * ss; o.w = accs[7] * ss;
        v4[1] = o;
        o.x = accv[0][0] * sv; o.y = accv[0][1] * sv;
        o.z = accv[0][2] * sv; o.w = accv[1][0] * sv;
        v4[2] = o;
        o.x = accv[1][1] * sv; o.y = accv[1][2] * sv;
        o.z = accv[2][0] * sv; o.w = accv[2][1] * sv;
        v4[3] = o;
        o.x = accv[2][2] * sv; o.y = accv[3][0] * sv;
        o.z = accv[3][1] * sv; o.w = accv[3][2] * sv;
        v4[4] = o;
        o.x = accv[4][0] * sv; o.y = accv[4][1] * sv;
        o.z = accv[4][2] * sv; o.w = accv[5][0] * sv;
        v4[5] = o;
        o.x = accv[5][1] * sv; o.y = accv[5][2] * sv;
        o.z = accv[6][0] * sv; o.w = accv[6][1] * sv;
        v4[6] = o;
        o.x = accv[6][2] * sv; o.y = accv[7][0] * sv;
        o.z = accv[7][1] * sv; o.w = accv[7][2] * sv;
        v4[7] = o;
      }
    }
  }
}

// ---------------- gather: one wave per node over its CSR segment ----------------
__global__ __launch_bounds__(256) void gather_kernel(
    const int* __restrict__ off,
    const float* __restrict__ exo,
    const float* __restrict__ wout,
    float* __restrict__ out)
{
  const int tid  = threadIdx.x;
  const int wave = tid >> 6;
  const int lane = tid & 63;
  const int n = blockIdx.x * 4 + wave;
  if (n >= NN) return;
  const int start = off[n];
  const int end   = off[n + 1];
  const int cnt   = end - start;

  float zp = 0.f;
  for (int j = start + lane; j < end; j += 64) zp += exo[j];
#pragma unroll
  for (int s = 32; s >= 1; s >>= 1) zp += __shfl_xor(zp, s, 64);

  const int l  = lane & 31;
  const int hh = lane >> 5;
  float acc = 0.f;
  for (int j = start + hh; j < end; j += 2)
    acc += wout[(size_t)j * 32 + l];
  acc += __shfl_xor(acc, 32, 64);

  if (lane < 32) {
    float s = (cnt > 0 && zp > 0.f) ? sqrtf((float)cnt / zp) : 0.f;
    out[(size_t)n * 32 + l] = acc * s;
  }
}

extern "C" void kernel_launch(void* const* d_in, const int* in_sizes, int n_in,
                              void* d_out, int out_size, void* d_ws, size_t ws_size,
                              hipStream_t stream)
{
  const float* node_attr  = (const float*)d_in[0];
  const int*   edge_index = (const int*)  d_in[1];
  const float* edge_attr  = (const float*)d_in[2];
  const float* edge_sh    = (const float*)d_in[3];
  const float* Wq0 = (const float*)d_in[4];
  const float* Wq1 = (const float*)d_in[5];
  const float* kW1 = (const float*)d_in[6];
  const float* kW2 = (const float*)d_in[7];
  const float* vW1 = (const float*)d_in[8];
  const float* vW2 = (const float*)d_in[9];
  const float* Wd0 = (const float*)d_in[10];
  const float* Wd1 = (const float*)d_in[11];
  float* out = (float*)d_out;

  float* ws = (float*)d_ws;
  float* qd     = ws;                    // 200000
  float* qvd    = qd   + 200000;         // 600000
  unsigned short* afrag  = (unsigned short*)(qvd + 600000);   // 40960 ushorts
  unsigned short* afrag1 = afrag + 40960;                     // 4096 ushorts
  int* hist   = (int*)(afrag1 + 4096);                        // 25024
  int* off    = hist + 25024;                                 // 25056 (NN+1)
  int* cursor = off  + 25056;                                 // 25024
  float* exo  = (float*)(cursor + 25024);                     // 200000
  float* wout = exo + 200000;                                 // 6400000

  hipMemsetAsync(hist, 0, 25024 * sizeof(int), stream);

  prep_kernel<<<160, 256, 0, stream>>>(
      kW1, kW2, vW1, vW2, node_attr, Wq0, Wq1, Wd0, Wd1, edge_index,
      afrag, afrag1, qd, qvd, hist);
  scan_kernel<<<1, 1024, 0, stream>>>(hist, off, cursor);
  edge_kernel<<<(NE + 255) / 256, 256, 0, stream>>>(
      node_attr, edge_index, edge_attr, edge_sh,
      afrag1, afrag, qd, qvd, cursor, exo, wout);
  gather_kernel<<<(NN + 3) / 4, 256, 0, stream>>>(off, exo, wout, out);
}